// Round 14
// baseline (4193.947 us; speedup 1.0000x reference)
//
#include <hip/hip_runtime.h>
#include <hip/hip_bf16.h>
#include <math.h>

#define Bn 2048
#define Vn 17
#define Cn 512
static const size_t NE = (size_t)Bn * Vn * Cn;   // 17,825,792
#define MROWS (Bn * Vn)                           // 34816 = 272 * 128

typedef __attribute__((ext_vector_type(8))) short bf16x8;
typedef __attribute__((ext_vector_type(4))) float f32x4;
typedef __attribute__((ext_vector_type(2))) float f32x2;
typedef unsigned short u16;

__device__ __forceinline__ float u2f(u16 u) { return __uint_as_float(((unsigned)u) << 16); }
__device__ __forceinline__ u16 f2u(float f) {
    unsigned u = __float_as_uint(f);
    return (u16)((u + 0x7fffu + ((u >> 16) & 1u)) >> 16);   // RNE fp32->bf16
}
__device__ __forceinline__ float gelu_f(float x) {
    return 0.5f * x * (1.0f + erff(x * 0.70710678118654752f));
}
__device__ __forceinline__ float exp2f_fast(float b) {
#if __has_builtin(__builtin_amdgcn_exp2f)
    return __builtin_amdgcn_exp2f(b);
#else
    return __expf(b * 0.69314718056f);
#endif
}
// tanh-form gelu: x * sigmoid(x*(1.5957691 + 0.0713548 x^2)); exp2-folded. max abs err ~1e-3
__device__ __forceinline__ float gelu_fast(float x) {
    float b = x * fmaf(x * x, -0.10294348f, -2.30220820f);
    return x * __builtin_amdgcn_rcpf(1.0f + exp2f_fast(b));
}
__device__ __forceinline__ unsigned pk2(float lo, float hi) {
    __hip_bfloat162 h = __float22bfloat162_rn(make_float2(lo, hi));
    unsigned r;
    __builtin_memcpy(&r, &h, 4);
    return r;
}
// two gelus via packed fp32 VALU; returns bf16x2 packed word
__device__ __forceinline__ unsigned gelu2pk(float x0, float x1) {
    f32x2 x = {x0, x1};
    f32x2 xx = x * x;
    f32x2 t = xx * (f32x2){-0.10294348f, -0.10294348f} +
              (f32x2){-2.30220820f, -2.30220820f};
    f32x2 b = x * t;
    f32x2 e = {exp2f_fast(b[0]), exp2f_fast(b[1])};
    f32x2 d = e + (f32x2){1.0f, 1.0f};
    f32x2 r = {__builtin_amdgcn_rcpf(d[0]), __builtin_amdgcn_rcpf(d[1])};
    f32x2 g = x * r;
    return pk2(g[0], g[1]);
}
__device__ __forceinline__ void gload16(const u16* g, u16* l) {
    __builtin_amdgcn_global_load_lds((const __attribute__((address_space(1))) void*)g,
                                     (__attribute__((address_space(3))) void*)l, 16, 0, 0);
}

// ---------------- diagnostic ----------------
__global__ void k_diag(float* __restrict__ o, float v, int n) {
    int i = blockIdx.x * 256 + threadIdx.x;
    if (i < n) o[i] = v;
}

// ---------------- fp32 -> bf16 weight conversion ----------------
__global__ void k_f2b(const float4* __restrict__ s, ushort4* __restrict__ d, int n4) {
    int i = blockIdx.x * 256 + threadIdx.x;
    if (i >= n4) return;
    float4 v = s[i];
    ushort4 o = {f2u(v.x), f2u(v.y), f2u(v.z), f2u(v.w)};
    d[i] = o;
}

// ---------------- MLP weight pad/convert ----------------
__global__ void k_mpad(const float* __restrict__ W1, const float* __restrict__ W2,
                       u16* __restrict__ W1p, u16* __restrict__ W2p) {
    int t = blockIdx.x * 256 + threadIdx.x;
    if (t < 512 * 32) {
        int o = t >> 5, j = t & 31;
        W1p[t] = (j < 17) ? f2u(W1[o * 17 + j]) : (u16)0;
    } else {
        int t2 = t - 512 * 32;
        int w = t2 >> 9;
        W2p[t2] = (w < 17) ? f2u(W2[t2]) : (u16)0;
    }
}

// ---------------- fused: xin = x + gelu(x) -> XIN bf16; LN_C(xin) -> T bf16 ----------------
__global__ __launch_bounds__(256) void k_xin_lnc(const float* __restrict__ X,
                                                 const float* __restrict__ g,
                                                 const float* __restrict__ bt,
                                                 u16* __restrict__ XIN, u16* __restrict__ T,
                                                 int nrows) {
    int row = blockIdx.x * 4 + (threadIdx.x >> 6);
    if (row >= nrows) return;
    int lane = threadIdx.x & 63;
    const float* xp = X + (size_t)row * Cn + lane * 8;
    float4 v0 = *(const float4*)xp, v1 = *(const float4*)(xp + 4);
    float xv[8] = {v0.x, v0.y, v0.z, v0.w, v1.x, v1.y, v1.z, v1.w};
    bf16x8 xr;
    float vv[8];
#pragma unroll
    for (int k = 0; k < 8; k++) {
        u16 h = f2u(xv[k] + gelu_f(xv[k]));
        xr[k] = (short)h;
        vv[k] = u2f(h);
    }
    *(bf16x8*)(XIN + (size_t)row * Cn + lane * 8) = xr;
    float s = 0.f, q = 0.f;
#pragma unroll
    for (int k = 0; k < 8; k++) { s += vv[k]; q = fmaf(vv[k], vv[k], q); }
#pragma unroll
    for (int o = 32; o; o >>= 1) { s += __shfl_xor(s, o); q += __shfl_xor(q, o); }
    float mean = s * (1.f / Cn);
    float var = q * (1.f / Cn) - mean * mean;
    float inv = 1.f / sqrtf(var + 1e-7f);
    int cb = lane * 8;
    bf16x8 r;
#pragma unroll
    for (int k = 0; k < 8; k++) r[k] = f2u((vv[k] - mean) * inv * g[cb + k] + bt[cb + k]);
    *(bf16x8*)(T + (size_t)row * Cn + cb) = r;
}

// ---------------- LayerNorm over C ----------------
template <int F32IO>
__global__ __launch_bounds__(256) void k_ln_c(const void* __restrict__ Xv,
                                              const float* __restrict__ g,
                                              const float* __restrict__ bt,
                                              void* __restrict__ Ov, int nrows) {
    int row = blockIdx.x * 4 + (threadIdx.x >> 6);
    if (row >= nrows) return;
    int lane = threadIdx.x & 63;
    float vv[8];
    if (F32IO) {
        const float* xp = (const float*)Xv + (size_t)row * Cn + lane * 8;
        float4 v0 = *(const float4*)xp, v1 = *(const float4*)(xp + 4);
        vv[0] = v0.x; vv[1] = v0.y; vv[2] = v0.z; vv[3] = v0.w;
        vv[4] = v1.x; vv[5] = v1.y; vv[6] = v1.z; vv[7] = v1.w;
    } else {
        bf16x8 h = *(const bf16x8*)((const u16*)Xv + (size_t)row * Cn + lane * 8);
#pragma unroll
        for (int k = 0; k < 8; k++) vv[k] = u2f((u16)h[k]);
    }
    float s = 0.f, q = 0.f;
#pragma unroll
    for (int k = 0; k < 8; k++) { s += vv[k]; q = fmaf(vv[k], vv[k], q); }
#pragma unroll
    for (int o = 32; o; o >>= 1) { s += __shfl_xor(s, o); q += __shfl_xor(q, o); }
    float mean = s * (1.f / Cn);
    float var = q * (1.f / Cn) - mean * mean;
    float inv = 1.f / sqrtf(var + 1e-7f);
    int cb = lane * 8;
    if (F32IO) {
        float r[8];
#pragma unroll
        for (int k = 0; k < 8; k++) r[k] = (vv[k] - mean) * inv * g[cb + k] + bt[cb + k];
        float* op = (float*)Ov + (size_t)row * Cn + cb;
        *(float4*)op = make_float4(r[0], r[1], r[2], r[3]);
        *(float4*)(op + 4) = make_float4(r[4], r[5], r[6], r[7]);
    } else {
        bf16x8 r;
#pragma unroll
        for (int k = 0; k < 8; k++) r[k] = f2u((vv[k] - mean) * inv * g[cb + k] + bt[cb + k]);
        *(bf16x8*)((u16*)Ov + (size_t)row * Cn + cb) = r;
    }
}

// ---------------- LayerNorm over J ----------------
__global__ __launch_bounds__(256) void k_ln_j(const u16* __restrict__ X,
                                              const float* __restrict__ g,
                                              const float* __restrict__ bt,
                                              u16* __restrict__ O) {
    int idx = blockIdx.x * 256 + threadIdx.x;
    int b = idx >> 9, c = idx & 511;
    const u16* xp = X + (size_t)b * Vn * Cn + c;
    float v[Vn];
    float s = 0.f;
#pragma unroll
    for (int j = 0; j < Vn; j++) { v[j] = u2f(xp[(size_t)j * Cn]); s += v[j]; }
    float mean = s * (1.f / Vn);
    float q = 0.f;
#pragma unroll
    for (int j = 0; j < Vn; j++) { float d = v[j] - mean; q = fmaf(d, d, q); }
    float inv = 1.f / sqrtf(q * (1.f / Vn) + 1e-7f);
    u16* op = O + (size_t)b * Vn * Cn + c;
#pragma unroll
    for (int j = 0; j < Vn; j++) op[(size_t)j * Cn] = f2u((v[j] - mean) * inv * g[j] + bt[j]);
}

// ---------------- fallback MFMA GEMM (direct-global; used only if CH<16) ----------------
template <int REMAP, int EPI>
__global__ __launch_bounds__(256) void k_gemm(const u16* __restrict__ A, const u16* __restrict__ W,
                                              const float* __restrict__ bias, u16* __restrict__ OutB,
                                              const u16* __restrict__ Res, float* __restrict__ Xf,
                                              int hbase, int shift) {
    constexpr int NT = REMAP ? 6 : 8;
    const int K = 512;
    int wave = threadIdx.x >> 6, lane = threadIdx.x & 63;
    int m0 = blockIdx.x * 128 + wave * 32;
    int nbase = blockIdx.y * (16 * NT);
    int r16 = lane & 15, kq = lane >> 4;
    int ld = REMAP ? (3 << shift) : 512;

    const u16* wp[NT];
    int wrow[NT];
#pragma unroll
    for (int nt = 0; nt < NT; nt++) {
        int n = nbase + nt * 16 + r16;
        int wr;
        if (REMAP) {
            int s = n >> shift, off = n & ((1 << shift) - 1);
            wr = (s << 9) + hbase + off;
        } else wr = n;
        wrow[nt] = wr;
        wp[nt] = W + (size_t)wr * K + kq * 8;
    }
    f32x4 acc[2][NT];
#pragma unroll
    for (int i = 0; i < 2; i++)
#pragma unroll
        for (int nt = 0; nt < NT; nt++) acc[i][nt] = (f32x4){0.f, 0.f, 0.f, 0.f};

    const u16* ap = A + (size_t)(m0 + r16) * K + kq * 8;
    for (int k0 = 0; k0 < K; k0 += 32) {
        bf16x8 a0 = *(const bf16x8*)(ap + k0);
        bf16x8 a1 = *(const bf16x8*)(ap + (size_t)16 * K + k0);
#pragma unroll
        for (int nt = 0; nt < NT; nt++) {
            bf16x8 bf = *(const bf16x8*)(wp[nt] + k0);
            acc[0][nt] = __builtin_amdgcn_mfma_f32_16x16x32_bf16(a0, bf, acc[0][nt], 0, 0, 0);
            acc[1][nt] = __builtin_amdgcn_mfma_f32_16x16x32_bf16(a1, bf, acc[1][nt], 0, 0, 0);
        }
    }
#pragma unroll
    for (int nt = 0; nt < NT; nt++) {
        float bv = bias[wrow[nt]];
        int n = nbase + nt * 16 + r16;
#pragma unroll
        for (int i = 0; i < 2; i++) {
#pragma unroll
            for (int r = 0; r < 4; r++) {
                size_t mb = (size_t)(m0 + i * 16 + kq * 4 + r);
                float v = acc[i][nt][r] + bv;
                if (EPI == 0) OutB[mb * ld + n] = f2u(v);
                else if (EPI == 1) { size_t o = mb * 512 + n; OutB[o] = f2u(v + u2f(Res[o])); }
                else { size_t o = mb * 512 + n; Xf[o] += v; }
            }
        }
    }
}

// ---------------- fast MFMA GEMM: 128x128 tile, BK=64 LDS staged, XCD-chunked panel-major ----------------
template <int EPI, int NY>
__global__ __launch_bounds__(256) void k_gemm2(const u16* __restrict__ A, const u16* __restrict__ W,
                                               const float* __restrict__ bias, u16* __restrict__ OutB,
                                               const u16* __restrict__ Res, float* __restrict__ Xf,
                                               int N) {
    __shared__ u16 As[128 * 64];
    __shared__ u16 Bs[128 * 64];
    const int K = 512;
    int tid = threadIdx.x;
    int wave = tid >> 6, lane = tid & 63;
    int cpx = gridDim.x >> 3;
    int bid = blockIdx.x;
    int swz = (bid & 7) * cpx + (bid >> 3);
    int m0 = (swz / NY) * 128, n0 = (swz % NY) * 128;
    int r16 = lane & 15, kq = lane >> 4;

    int srow = wave << 2;
    int lrow = lane >> 3;
    int lcol = (lane & 7) * 8;

    f32x4 acc[2][8];
#pragma unroll
    for (int i = 0; i < 2; i++)
#pragma unroll
        for (int j = 0; j < 8; j++) acc[i][j] = (f32x4){0.f, 0.f, 0.f, 0.f};

    const u16* aT = As + (wave * 32 + r16) * 64 + kq * 8;
    const u16* bT = Bs + r16 * 64 + kq * 8;

    for (int k0 = 0; k0 < K; k0 += 64) {
#pragma unroll
        for (int i = 0; i < 4; i++) {
            int rows = (srow + i) * 8 + lrow;
            gload16(A + (size_t)(m0 + rows) * K + k0 + lcol, (u16*)As + (srow + i) * 512);
            gload16(W + (size_t)(n0 + rows) * K + k0 + lcol, (u16*)Bs + (srow + i) * 512);
        }
        __syncthreads();
#pragma unroll
        for (int kk = 0; kk < 64; kk += 32) {
            bf16x8 af0 = *(const bf16x8*)(aT + kk);
            bf16x8 af1 = *(const bf16x8*)(aT + 16 * 64 + kk);
#pragma unroll
            for (int nt = 0; nt < 8; nt++) {
                bf16x8 bf = *(const bf16x8*)(bT + nt * 16 * 64 + kk);
                acc[0][nt] = __builtin_amdgcn_mfma_f32_16x16x32_bf16(af0, bf, acc[0][nt], 0, 0, 0);
                acc[1][nt] = __builtin_amdgcn_mfma_f32_16x16x32_bf16(af1, bf, acc[1][nt], 0, 0, 0);
            }
        }
        __syncthreads();
    }

    int mw = m0 + wave * 32;
#pragma unroll
    for (int nt = 0; nt < 8; nt++) {
        int n = n0 + nt * 16 + r16;
        float bv = bias[n];
#pragma unroll
        for (int i = 0; i < 2; i++) {
#pragma unroll
            for (int r = 0; r < 4; r++) {
                size_t mb = (size_t)(mw + i * 16 + kq * 4 + r);
                size_t o = mb * N + n;
                float v = acc[i][nt][r] + bv;
                if (EPI == 0) OutB[o] = f2u(v);
                else if (EPI == 1) OutB[o] = f2u(v + u2f(Res[o]));
                else Xf[o] += v;
            }
        }
    }
}

// ---------------- FUSED QKV-GEMM + attention: block = (7 batches, 1 head) ----------------
// GEMM: A(119->128 rows x 512) @ Wsub(96x512)^T + bias -> Ys[128][104] bf16 in LDS
// (Ys aliases As/Bs staging; bf16 rounding matches the old Y buffer exactly).
// Then per-(batch,head) attention from LDS; writes only the attended 32 cols.
__global__ __launch_bounds__(256) void k_fat(const u16* __restrict__ A, const u16* __restrict__ W,
                                             const float* __restrict__ bias, u16* __restrict__ T) {
    __shared__ char smem[28672];
    u16* As = (u16*)smem;             // [128][64]
    u16* Bs = (u16*)(smem + 16384);   // [96][64]
    u16* Ys = (u16*)smem;             // [128][104] (aliases As/Bs after final barrier)
    const int K = 512;
    int tid = threadIdx.x;
    int wave = tid >> 6, lane = tid & 63;
    int mb = blockIdx.x >> 4;         // 0..292
    int h = blockIdx.x & 15;
    int m0 = mb * 119;
    int r16 = lane & 15, kq = lane >> 4;
    int lrow = lane >> 3;
    int lcol = (lane & 7) * 8;

    f32x4 acc[2][6];
#pragma unroll
    for (int i = 0; i < 2; i++)
#pragma unroll
        for (int nt = 0; nt < 6; nt++) acc[i][nt] = (f32x4){0.f, 0.f, 0.f, 0.f};

    const u16* aT = As + (wave * 32 + r16) * 64 + kq * 8;
    const u16* bT = Bs + r16 * 64 + kq * 8;

    for (int k0 = 0; k0 < K; k0 += 64) {
#pragma unroll
        for (int i = 0; i < 4; i++) {
            int rows = (wave * 4 + i) * 8 + lrow;           // 0..127
            int grow = m0 + rows;
            if (grow > MROWS - 1) grow = MROWS - 1;         // tail clamp (in-bounds read)
            gload16(A + (size_t)grow * K + k0 + lcol, As + (wave * 4 + i) * 512);
        }
#pragma unroll
        for (int i = 0; i < 3; i++) {
            int rw = (wave * 3 + i) * 8 + lrow;             // 0..95
            int wr = ((rw >> 5) << 9) + h * 32 + (rw & 31); // s*512 + h*32 + off
            gload16(W + (size_t)wr * K + k0 + lcol, Bs + (wave * 3 + i) * 512);
        }
        __syncthreads();
#pragma unroll
        for (int kk = 0; kk < 64; kk += 32) {
            bf16x8 af0 = *(const bf16x8*)(aT + kk);
            bf16x8 af1 = *(const bf16x8*)(aT + 16 * 64 + kk);
#pragma unroll
            for (int nt = 0; nt < 6; nt++) {
                bf16x8 bf = *(const bf16x8*)(bT + nt * 16 * 64 + kk);
                acc[0][nt] = __builtin_amdgcn_mfma_f32_16x16x32_bf16(af0, bf, acc[0][nt], 0, 0, 0);
                acc[1][nt] = __builtin_amdgcn_mfma_f32_16x16x32_bf16(af1, bf, acc[1][nt], 0, 0, 0);
            }
        }
        __syncthreads();   // all MFMA reads of As/Bs complete -> safe to alias with Ys
    }

    // bias + bf16 round -> Ys. D layout: col = nt*16 + r16, row = wave*32 + i*16 + kq*4 + r
#pragma unroll
    for (int nt = 0; nt < 6; nt++) {
        int col = nt * 16 + r16;
        int wr = ((col >> 5) << 9) + h * 32 + (col & 31);
        float bv = bias[wr];
#pragma unroll
        for (int i = 0; i < 2; i++) {
            int row = wave * 32 + i * 16 + kq * 4;
#pragma unroll
            for (int r = 0; r < 4; r++)
                Ys[(row + r) * 104 + col] = f2u(acc[i][nt][r] + bv);
        }
    }
    __syncthreads();

    // ---- attention epilogue (same math as k_attn), Q=cols 0..31, K=32..63, V=64..95 ----
    int which = (lane >= 17) ? 1 : 0;
    int j = lane - which * 17;
    int bl = wave * 2 + which;
    if (lane < 34 && bl < 7) {
        int b = mb * 7 + bl;
        if (b < Bn) {
            const u16* yb = Ys + (size_t)(bl * 17) * 104;
            float q[32];
#pragma unroll
            for (int d0 = 0; d0 < 32; d0 += 8) {
                bf16x8 hq = *(const bf16x8*)(yb + j * 104 + d0);
#pragma unroll
                for (int d = 0; d < 8; d++) q[d0 + d] = u2f((u16)hq[d]);
            }
            float sc[Vn];
            float mx = -1e30f;
#pragma unroll
            for (int kk = 0; kk < Vn; kk++) {
                const u16* kb = yb + kk * 104 + 32;
                float s = 0.f;
#pragma unroll
                for (int d0 = 0; d0 < 32; d0 += 8) {
                    bf16x8 hk = *(const bf16x8*)(kb + d0);
#pragma unroll
                    for (int d = 0; d < 8; d++) s = fmaf(q[d0 + d], u2f((u16)hk[d]), s);
                }
                s *= 0.1767766952966369f;
                sc[kk] = s;
                mx = fmaxf(mx, s);
            }
            float sum = 0.f;
#pragma unroll
            for (int kk = 0; kk < Vn; kk++) { sc[kk] = __expf(sc[kk] - mx); sum += sc[kk]; }
            float inv = 1.f / sum;
            float o[32];
#pragma unroll
            for (int d = 0; d < 32; d++) o[d] = 0.f;
#pragma unroll
            for (int kk = 0; kk < Vn; kk++) {
                const u16* vb = yb + kk * 104 + 64;
                float p = sc[kk] * inv;
#pragma unroll
                for (int d0 = 0; d0 < 32; d0 += 8) {
                    bf16x8 hv = *(const bf16x8*)(vb + d0);
#pragma unroll
                    for (int d = 0; d < 8; d++) o[d0 + d] = fmaf(p, u2f((u16)hv[d]), o[d0 + d]);
                }
            }
            u16* op = T + (size_t)(b * Vn + j) * Cn + h * 32;
#pragma unroll
            for (int d0 = 0; d0 < 32; d0 += 8) {
                bf16x8 r;
#pragma unroll
                for (int d = 0; d < 8; d++) r[d] = f2u(o[d0 + d]);
                *(bf16x8*)(op + d0) = r;
            }
        }
    }
}

// ---------------- attention on chunked QKV (fallback path) ----------------
__global__ __launch_bounds__(256) void k_attn(const u16* __restrict__ Y, u16* __restrict__ T,
                                              int shift, int hgbase, int l2ch) {
    int wv = threadIdx.x >> 6, lane = threadIdx.x & 63;
    if (lane >= 34) return;
    int gw = blockIdx.x * 4 + wv;
    int which = (lane >= 17) ? 1 : 0;
    int j = lane - which * 17;
    int pid = gw * 2 + which;
    int b = pid >> l2ch;
    int hl = pid & ((1 << l2ch) - 1);
    int CW = 1 << shift;
    int row3 = 3 << shift;

    const u16* qb = Y + (size_t)(b * Vn + j) * row3 + hl * 32;
    float q[32];
#pragma unroll
    for (int d0 = 0; d0 < 32; d0 += 8) {
        bf16x8 h = *(const bf16x8*)(qb + d0);
#pragma unroll
        for (int d = 0; d < 8; d++) q[d0 + d] = u2f((u16)h[d]);
    }
    float sc[Vn];
    float mx = -1e30f;
#pragma unroll
    for (int kk = 0; kk < Vn; kk++) {
        const u16* kb = Y + (size_t)(b * Vn + kk) * row3 + CW + hl * 32;
        float s = 0.f;
#pragma unroll
        for (int d0 = 0; d0 < 32; d0 += 8) {
            bf16x8 h = *(const bf16x8*)(kb + d0);
#pragma unroll
            for (int d = 0; d < 8; d++) s = fmaf(q[d0 + d], u2f((u16)h[d]), s);
        }
        s *= 0.1767766952966369f;
        sc[kk] = s;
        mx = fmaxf(mx, s);
    }
    float sum = 0.f;
#pragma unroll
    for (int kk = 0; kk < Vn; kk++) { sc[kk] = __expf(sc[kk] - mx); sum += sc[kk]; }
    float inv = 1.f / sum;
    float o[32];
#pragma unroll
    for (int d = 0; d < 32; d++) o[d] = 0.f;
#pragma unroll
    for (int kk = 0; kk < Vn; kk++) {
        const u16* vb = Y + (size_t)(b * Vn + kk) * row3 + 2 * CW + hl * 32;
        float p = sc[kk] * inv;
#pragma unroll
        for (int d0 = 0; d0 < 32; d0 += 8) {
            bf16x8 h = *(const bf16x8*)(vb + d0);
#pragma unroll
            for (int d = 0; d < 8; d++) o[d0 + d] = fmaf(p, u2f((u16)h[d]), o[d0 + d]);
        }
    }
    u16* op = T + (size_t)(b * Vn + j) * Cn + hgbase + hl * 32;
#pragma unroll
    for (int d0 = 0; d0 < 32; d0 += 8) {
        bf16x8 r;
#pragma unroll
        for (int d = 0; d < 8; d++) r[d] = f2u(o[d0 + d]);
        *(bf16x8*)(op + d0) = r;
    }
}

// ---------------- GCN aggregation + fused adds ----------------
template <int MODE>
__global__ __launch_bounds__(256) void k_agg(const u16* __restrict__ Y, const float* __restrict__ Adj,
                                             const u16* __restrict__ aux1, const u16* __restrict__ aux2,
                                             u16* __restrict__ OutB, float* __restrict__ Xf,
                                             int cbase, int shift) {
    __shared__ float adj_s[3][Vn][Vn];
    for (int t = threadIdx.x; t < 3 * Vn * Vn; t += 256) {
        int k = t / (Vn * Vn), r = t - k * Vn * Vn;
        adj_s[k][r / Vn][r % Vn] = Adj[t];
    }
    __syncthreads();
    int CW = 1 << shift;
    int idx = blockIdx.x * 256 + threadIdx.x;
    int b = idx >> shift, co = idx & (CW - 1);
    int c = cbase + co;
    int row3 = 3 << shift;
    float acc[Vn];
#pragma unroll
    for (int w = 0; w < Vn; w++) acc[w] = 0.f;
    const u16* yb = Y + (size_t)b * Vn * row3 + co;
#pragma unroll
    for (int k = 0; k < 3; k++)
#pragma unroll
        for (int v = 0; v < Vn; v++) {
            float y = u2f(yb[(size_t)v * row3 + k * CW]);
#pragma unroll
            for (int w = 0; w < Vn; w++) acc[w] = fmaf(y, adj_s[k][v][w], acc[w]);
        }
    size_t rb = (size_t)(b * Vn) * Cn + c;
#pragma unroll
    for (int w = 0; w < Vn; w++) {
        size_t o = rb + (size_t)w * Cn;
        float val = acc[w] + u2f(aux1[o]) + u2f(aux2[o]);
        if (MODE == 0) OutB[o] = f2u(val);
        else Xf[o] += val;
    }
}

// ---------------- MFMA token-MLP v9 (round-13, packed gelu) ----------------
__global__ __launch_bounds__(512) void k_mlp(const u16* __restrict__ X,
                                             const u16* __restrict__ W1p, const float* __restrict__ B1,
                                             const u16* __restrict__ W2p, const float* __restrict__ B2,
                                             u16* __restrict__ O) {
    __shared__ u16 Xs[256 * 40];
    __shared__ u16 Hs[256 * 40];
    int b = blockIdx.x >> 1;
    int cbase = (blockIdx.x & 1) << 8;
    int tid = threadIdx.x;

    for (int i = tid; i < 256 * 40 / 8; i += 512) ((float4*)Xs)[i] = make_float4(0.f, 0.f, 0.f, 0.f);
    __syncthreads();
    const u16* xb = X + (size_t)b * (Vn * Cn) + cbase;
    for (int i = tid; i < 17 * 256; i += 512) {
        int j = i >> 8, c = i & 255;
        Xs[c * 40 + j] = xb[j * Cn + c];
    }
    __syncthreads();

    int wave = tid >> 6, lane = tid & 63;
    int r16 = lane & 15, kq = lane >> 4;
    int crow = wave * 32;

    bf16x8 xf0 = *(const bf16x8*)(Xs + (crow + r16) * 40 + kq * 8);
    bf16x8 xf1 = *(const bf16x8*)(Xs + (crow + 16 + r16) * 40 + kq * 8);

    f32x4 acc2[2][2];
#pragma unroll
    for (int i = 0; i < 2; i++)
#pragma unroll
        for (int j = 0; j < 2; j++) acc2[i][j] = (f32x4){0.f, 0.f, 0.f, 0.f};

    const u16* hs0 = Hs + (crow + r16) * 40 + kq * 8;
    const u16* w1b = W1p + (r16 << 5) + kq * 8;
    const u16* w2b = W2p + (size_t)r16 * 512 + kq * 8;
    const u16* w2c = W2p + (size_t)16 * 512 + kq * 8;
    const float* b1b = B1 + kq * 4;

#pragma unroll
    for (int s = 0; s < 16; s++) {
        bf16x8 af0 = *(const bf16x8*)(w1b + s * 1024);
        bf16x8 af1 = *(const bf16x8*)(w1b + s * 1024 + 512);
        f32x4 bi0 = *(const f32x4*)(b1b + s * 32);
        f32x4 bi1 = *(const f32x4*)(b1b + s * 32 + 16);
        f32x4 a00 = __builtin_amdgcn_mfma_f32_16x16x32_bf16(af0, xf0, bi0, 0, 0, 0);
        f32x4 a01 = __builtin_amdgcn_mfma_f32_16x16x32_bf16(af0, xf1, bi0, 0, 0, 0);
        f32x4 a10 = __builtin_amdgcn_mfma_f32_16x16x32_bf16(af1, xf0, bi1, 0, 0, 0);
        f32x4 a11 = __builtin_amdgcn_mfma_f32_16x16x32_bf16(af1, xf1, bi1, 0, 0, 0);
#define STORE_H(ACC, NT, OT)                                                             \
        {                                                                                 \
            unsigned g0 = gelu2pk(ACC[0], ACC[1]);                                        \
            unsigned g1 = gelu2pk(ACC[2], ACC[3]);                                        \
            *(uint2*)(Hs + (crow + NT * 16 + r16) * 40 + OT * 16 + kq * 4) =              \
                make_uint2(g0, g1);                                                       \
        }
        STORE_H(a00, 0, 0)
        STORE_H(a01, 1, 0)
        STORE_H(a10, 0, 1)
        STORE_H(a11, 1, 1)
#undef STORE_H
        __builtin_amdgcn_sched_barrier(0);
        bf16x8 h0 = *(const bf16x8*)hs0;
        bf16x8 h1 = *(const bf16x8*)(hs0 + 16 * 40);
        bf16x8 wf0 = *(const bf16x8*)(w2b + s * 32);
        bf16x8 wf1 = *(const bf16x8*)(w2c + s * 32);
        acc2[0][0] = __builtin_amdgcn_mfma_f32_16x16x32_bf16(h0, wf0, acc2[0][0], 0, 0, 0);
        acc2[0][1] = __builtin_amdgcn_mfma_f32_16x16x32_bf16(h0, wf1, acc2[0][1], 0, 0, 0);
        acc2[1][0] = __builtin_amdgcn_mfma_f32_16x16x32_bf16(h1, wf0, acc2[1][0], 0, 0, 0);
        acc2[1][1] = __builtin_amdgcn_mfma_f32_16x16x32_bf16(h1, wf1, acc2[1][1], 0, 0, 0);
    }

    u16* ob = O + (size_t)b * (Vn * Cn) + cbase;
#pragma unroll
    for (int nt = 0; nt < 2; nt++) {
        int cl = crow + nt * 16 + kq * 4;
#pragma unroll
        for (int n2 = 0; n2 < 2; n2++) {
            int w = n2 * 16 + r16;
            if (w < 17) {
                float bb = B2[w];
                f32x4 v = acc2[nt][n2];
                uint2 pk = make_uint2(gelu2pk(v[0] + bb, v[1] + bb),
                                      gelu2pk(v[2] + bb, v[3] + bb));
                *(uint2*)(ob + (size_t)w * Cn + cl) = pk;
            }
        }
    }
}

// ---------------- orchestration ----------------
extern "C" void kernel_launch(void* const* d_in, const int* in_sizes, int n_in,
                              void* d_out, int out_size, void* d_ws, size_t ws_size,
                              hipStream_t stream) {
    (void)in_sizes; (void)n_in; (void)out_size;
    typedef const float* fp;
    fp x_in = (fp)d_in[0];
    fp adj = (fp)d_in[1];
    fp ln1_g = (fp)d_in[2], ln1_b = (fp)d_in[3];
    fp ln2_g = (fp)d_in[4], ln2_b = (fp)d_in[5];
    fp gcn1_w = (fp)d_in[6], gcn1_b = (fp)d_in[7];
    fp gcn2_w = (fp)d_in[8], gcn2_b = (fp)d_in[9];
    fp m1w = (fp)d_in[10], m1b = (fp)d_in[11];
    fp m2w = (fp)d_in[12], m2b = (fp)d_in[13];
    fp aln_g = (fp)d_in[14], aln_b = (fp)d_in[15];
    fp qkv1_w = (fp)d_in[16], qkv1_b = (fp)d_in[17];
    fp p1w = (fp)d_in[18], p1b = (fp)d_in[19];
    fp qkv2_w = (fp)d_in[20], qkv2_b = (fp)d_in[21];
    fp p2w = (fp)d_in[22], p2b = (fp)d_in[23];
    fp tn_g = (fp)d_in[24], tn_b = (fp)d_in[25];

    const size_t NE2 = NE * 2;
    const size_t YCH16 = (size_t)MROWS * 96 * 16 * 2;
    const size_t SZ_QKV3 = (size_t)3 * 1536 * 512;
    const size_t SZ_P3 = (size_t)3 * 512 * 512;
    const size_t MPADL = (size_t)(512 * 32 + 32 * 512);
    const size_t POOLB = (4 * SZ_QKV3 + 2 * SZ_P3 + 3 * MPADL) * 2;
    const size_t WSCR_SZ = (size_t)1536 * 512 * 2;
    const size_t MPAD_SZ = MPADL * 2;

    bool FULLW = false;
    int CH = 0;
    if (3 * NE2 + YCH16 + POOLB + 1024 <= ws_size) { FULLW = true; CH = 16; }
    else {
        for (int ch = 16; ch >= 1; ch >>= 1) {
            size_t need = 3 * NE2 + WSCR_SZ + MPAD_SZ + (size_t)MROWS * 96 * ch * 2 + 1024;
            if (need <= ws_size) { CH = ch; break; }
        }
    }
    if (!CH) {
        k_diag<<<(int)((NE + 255) / 256), 256, 0, stream>>>((float*)d_out, (float)ws_size, (int)NE);
        return;
    }
    const int l2ch = __builtin_ctz(CH);
    const int shift = 5 + l2ch;
    const int NCH = 16 / CH;
    const bool FAST = (CH == 16);

    char* p = (char*)d_ws;
    u16* XIN = (u16*)p;  p += NE2;
    u16* T1 = (u16*)p;   p += NE2;
    u16* T2 = (u16*)p;   p += NE2;
    u16* YCH = (u16*)p;  p += (size_t)MROWS * 96 * CH * 2;
    u16 *WQ1 = nullptr, *WQ2 = nullptr, *WG1 = nullptr, *WG2 = nullptr,
        *WP1 = nullptr, *WP2 = nullptr, *MP1 = nullptr, *MP2 = nullptr, *WSCR = nullptr;
    if (FULLW) {
        WQ1 = (u16*)p; p += SZ_QKV3 * 2;
        WQ2 = (u16*)p; p += SZ_QKV3 * 2;
        WG1 = (u16*)p; p += SZ_QKV3 * 2;
        WG2 = (u16*)p; p += SZ_QKV3 * 2;
        WP1 = (u16*)p; p += SZ_P3 * 2;
        WP2 = (u16*)p; p += SZ_P3 * 2;
        MP1 = (u16*)p; p += 3 * 16384 * 2;
        MP2 = (u16*)p; p += 3 * 16384 * 2;
    } else {
        WSCR = (u16*)p; p += WSCR_SZ;
        MP1 = (u16*)p;  p += 16384 * 2;
        MP2 = (u16*)p;
    }

    float* X = (float*)d_out;
    (void)hipMemcpyAsync(X, x_in, NE * 4, hipMemcpyDeviceToDevice, stream);

    if (FULLW) {
        k_f2b<<<2304, 256, 0, stream>>>((const float4*)qkv1_w, (ushort4*)WQ1, (int)(SZ_QKV3 / 4));
        k_f2b<<<2304, 256, 0, stream>>>((const float4*)qkv2_w, (ushort4*)WQ2, (int)(SZ_QKV3 / 4));
        k_f2b<<<2304, 256, 0, stream>>>((const float4*)gcn1_w, (ushort4*)WG1, (int)(SZ_QKV3 / 4));
        k_f2b<<<2304, 256, 0, stream>>>((const float4*)gcn2_w, (ushort4*)WG2, (int)(SZ_QKV3 / 4));
        k_f2b<<<768, 256, 0, stream>>>((const float4*)p1w, (ushort4*)WP1, (int)(SZ_P3 / 4));
        k_f2b<<<768, 256, 0, stream>>>((const float4*)p2w, (ushort4*)WP2, (int)(SZ_P3 / 4));
        for (int l = 0; l < 3; l++)
            k_mpad<<<128, 256, 0, stream>>>(m1w + (size_t)l * Cn * Vn, m2w + (size_t)l * Vn * Cn,
                                            MP1 + l * 16384, MP2 + l * 16384);
    }

    const int GLN = MROWS / 4;
    const int GBC = Bn * Cn / 256;
    const int GATT = (Bn << l2ch) / 8;
    const int GAGG = (Bn << shift) / 256;
    const dim3 GEMM_C(MROWS / 128, CH);
    const dim3 GEMM_P(MROWS / 128, 4);
    const int CV_QKV = (int)(1536 * 512 / 4 / 256);
    const int CV_P = (int)(512 * 512 / 4 / 256);
    const int GQF = (MROWS / 128) * 12;
    const int GPF = (MROWS / 128) * 4;
    const int GFAT = 293 * 16;   // ceil(2048/7) * 16 heads

    for (int i = 0; i < 3; i++) {
        fp q1w = qkv1_w + (size_t)i * 1536 * 512, q1b = qkv1_b + i * 1536;
        fp q2w = qkv2_w + (size_t)i * 1536 * 512, q2b = qkv2_b + i * 1536;
        fp g1w = gcn1_w + (size_t)i * 1536 * 512, g1b = gcn1_b + i * 1536;
        fp g2w = gcn2_w + (size_t)i * 1536 * 512, g2b = gcn2_b + i * 1536;
        fp pw1 = p1w + (size_t)i * 512 * 512, pb1 = p1b + i * Cn;
        fp pw2 = p2w + (size_t)i * 512 * 512, pb2 = p2b + i * Cn;
        fp alg = aln_g + i * Cn, alb = aln_b + i * Cn;
        fp l1g = ln1_g + i * Vn, l1b_ = ln1_b + i * Vn;
        fp l2g = ln2_g + i * Cn, l2b_ = ln2_b + i * Cn;
        fp w1 = m1w + (size_t)i * Cn * Vn, b1 = m1b + i * Cn;
        fp w2 = m2w + (size_t)i * Vn * Cn, b2 = m2b + i * Vn;

        const u16* wq1p = FULLW ? WQ1 + (size_t)i * 1536 * 512 : WSCR;
        const u16* wq2p = FULLW ? WQ2 + (size_t)i * 1536 * 512 : WSCR;
        const u16* wg1p = FULLW ? WG1 + (size_t)i * 1536 * 512 : WSCR;
        const u16* wg2p = FULLW ? WG2 + (size_t)i * 1536 * 512 : WSCR;
        const u16* wp1p = FULLW ? WP1 + (size_t)i * 512 * 512 : WSCR;
        const u16* wp2p = FULLW ? WP2 + (size_t)i * 512 * 512 : WSCR;
        const u16* mp1 = FULLW ? MP1 + i * 16384 : MP1;
        const u16* mp2 = FULLW ? MP2 + i * 16384 : MP2;

        if (!FULLW) k_mpad<<<128, 256, 0, stream>>>(w1, w2, (u16*)mp1, (u16*)mp2);

        // ---------- gkpc ----------
        k_xin_lnc<<<GLN, 256, 0, stream>>>(X, alg, alb, XIN, T1, MROWS);
        if (!FULLW) k_f2b<<<CV_QKV, 256, 0, stream>>>((const float4*)q1w, (ushort4*)WSCR, 1536 * 512 / 4);
        if (FAST) {
            k_fat<<<GFAT, 256, 0, stream>>>(T1, wq1p, q1b, T2);
        } else {
            for (int hg = 0; hg < NCH; hg++) {
                k_gemm<1, 0><<<GEMM_C, 256, 0, stream>>>(T1, WSCR, q1b, YCH, nullptr, nullptr, hg << shift, shift);
                k_attn<<<GATT, 256, 0, stream>>>(YCH, T2, shift, hg << shift, l2ch);
            }
        }
        if (!FULLW) k_f2b<<<CV_P, 256, 0, stream>>>((const float4*)pw1, (ushort4*)WSCR, 512 * 512 / 4);
        if (FAST) k_gemm2<1, 4><<<GPF, 256, 0, stream>>>(T2, wp1p, pb1, T1, XIN, nullptr, 512);
        else k_gemm<0, 1><<<GEMM_P, 256, 0, stream>>>(T2, WSCR, pb1, T1, XIN, nullptr, 0, 0);
        k_ln_c<0><<<GLN, 256, 0, stream>>>(T1, alg, alb, T2, MROWS);
        if (!FULLW) k_f2b<<<CV_QKV, 256, 0, stream>>>((const float4*)q2w, (ushort4*)WSCR, 1536 * 512 / 4);
        if (FAST) {
            k_fat<<<GFAT, 256, 0, stream>>>(T2, wq2p, q2b, T1);
        } else {
            for (int hg = 0; hg < NCH; hg++) {
                k_gemm<1, 0><<<GEMM_C, 256, 0, stream>>>(T2, WSCR, q2b, YCH, nullptr, nullptr, hg << shift, shift);
                k_attn<<<GATT, 256, 0, stream>>>(YCH, T1, shift, hg << shift, l2ch);
            }
        }
        if (!FULLW) k_f2b<<<CV_P, 256, 0, stream>>>((const float4*)pw2, (ushort4*)WSCR, 512 * 512 / 4);
        if (FAST) k_gemm2<2, 4><<<GPF, 256, 0, stream>>>(T1, wp2p, pb2, nullptr, nullptr, X, 512);
        else k_gemm<0, 2><<<GEMM_P, 256, 0, stream>>>(T1, WSCR, pb2, nullptr, nullptr, X, 0, 0);

        // ---------- lrsc ----------
        k_ln_j<<<GBC, 256, 0, stream>>>(XIN, l1g, l1b_, T1);
        k_mlp<<<Bn * 2, 512, 0, stream>>>(T1, mp1, b1, mp2, b2, T2);
        if (!FULLW) k_f2b<<<CV_QKV, 256, 0, stream>>>((const float4*)g1w, (ushort4*)WSCR, 1536 * 512 / 4);
        if (FAST) {
            k_gemm2<0, 12><<<GQF, 256, 0, stream>>>(T1, wg1p, g1b, YCH, nullptr, nullptr, 1536);
            k_agg<0><<<GAGG, 256, 0, stream>>>(YCH, adj, XIN, T2, XIN, nullptr, 0, shift);
        } else {
            for (int cc = 0; cc < NCH; cc++) {
                k_gemm<1, 0><<<GEMM_C, 256, 0, stream>>>(T1, WSCR, g1b, YCH, nullptr, nullptr, cc << shift, shift);
                k_agg<0><<<GAGG, 256, 0, stream>>>(YCH, adj, XIN, T2, XIN, nullptr, cc << shift, shift);
            }
        }
        k_ln_c<0><<<GLN, 256, 0, stream>>>(XIN, l2g, l2b_, T1, MROWS);
        k_mlp<<<Bn * 2, 512, 0, stream>>>(T1, mp1, b1, mp2, b2, T2);
        if (!FULLW) k_f2b<<<CV_QKV, 256, 0, stream>>>((const float4*)g2w, (ushort4*)WSCR, 1536 * 512 / 4);
        if (FAST) {
            k_gemm2<0, 12><<<GQF, 256, 0, stream>>>(T1, wg2p, g2b, YCH, nullptr, nullptr, 1536);
            k_agg<1><<<GAGG, 256, 0, stream>>>(YCH, adj, T1, T2, nullptr, X, 0, shift);
        } else {
            for (int cc = 0; cc < NCH; cc++) {
                k_gemm<1, 0><<<GEMM_C, 256, 0, stream>>>(T1, WSCR, g2b, YCH, nullptr, nullptr, cc << shift, shift);
                k_agg<1><<<GAGG, 256, 0, stream>>>(YCH, adj, T1, T2, nullptr, X, cc << shift, shift);
            }
        }
    }

    k_ln_c<1><<<GLN, 256, 0, stream>>>(X, tn_g, tn_b, X, MROWS);
}

// Round 15
// 3711.325 us; speedup vs baseline: 1.1300x; 1.1300x over previous
//
#include <hip/hip_runtime.h>
#include <hip/hip_bf16.h>
#include <math.h>

#define Bn 2048
#define Vn 17
#define Cn 512
static const size_t NE = (size_t)Bn * Vn * Cn;   // 17,825,792
#define MROWS (Bn * Vn)                           // 34816 = 272 * 128

typedef __attribute__((ext_vector_type(8))) short bf16x8;
typedef __attribute__((ext_vector_type(4))) float f32x4;
typedef __attribute__((ext_vector_type(2))) float f32x2;
typedef unsigned short u16;

__device__ __forceinline__ float u2f(u16 u) { return __uint_as_float(((unsigned)u) << 16); }
__device__ __forceinline__ u16 f2u(float f) {
    unsigned u = __float_as_uint(f);
    return (u16)((u + 0x7fffu + ((u >> 16) & 1u)) >> 16);   // RNE fp32->bf16
}
__device__ __forceinline__ float gelu_f(float x) {
    return 0.5f * x * (1.0f + erff(x * 0.70710678118654752f));
}
__device__ __forceinline__ float exp2f_fast(float b) {
#if __has_builtin(__builtin_amdgcn_exp2f)
    return __builtin_amdgcn_exp2f(b);
#else
    return __expf(b * 0.69314718056f);
#endif
}
// tanh-form gelu: x * sigmoid(x*(1.5957691 + 0.0713548 x^2)); exp2-folded. max abs err ~1e-3
__device__ __forceinline__ float gelu_fast(float x) {
    float b = x * fmaf(x * x, -0.10294348f, -2.30220820f);
    return x * __builtin_amdgcn_rcpf(1.0f + exp2f_fast(b));
}
__device__ __forceinline__ unsigned pk2(float lo, float hi) {
    __hip_bfloat162 h = __float22bfloat162_rn(make_float2(lo, hi));
    unsigned r;
    __builtin_memcpy(&r, &h, 4);
    return r;
}
// two gelus via packed fp32 VALU; returns bf16x2 packed word
__device__ __forceinline__ unsigned gelu2pk(float x0, float x1) {
    f32x2 x = {x0, x1};
    f32x2 xx = x * x;
    f32x2 t = xx * (f32x2){-0.10294348f, -0.10294348f} +
              (f32x2){-2.30220820f, -2.30220820f};
    f32x2 b = x * t;
    f32x2 e = {exp2f_fast(b[0]), exp2f_fast(b[1])};
    f32x2 d = e + (f32x2){1.0f, 1.0f};
    f32x2 r = {__builtin_amdgcn_rcpf(d[0]), __builtin_amdgcn_rcpf(d[1])};
    f32x2 g = x * r;
    return pk2(g[0], g[1]);
}
__device__ __forceinline__ void gload16(const u16* g, u16* l) {
    __builtin_amdgcn_global_load_lds((const __attribute__((address_space(1))) void*)g,
                                     (__attribute__((address_space(3))) void*)l, 16, 0, 0);
}

// ---------------- diagnostic ----------------
__global__ void k_diag(float* __restrict__ o, float v, int n) {
    int i = blockIdx.x * 256 + threadIdx.x;
    if (i < n) o[i] = v;
}

// ---------------- fp32 -> bf16 weight conversion ----------------
__global__ void k_f2b(const float4* __restrict__ s, ushort4* __restrict__ d, int n4) {
    int i = blockIdx.x * 256 + threadIdx.x;
    if (i >= n4) return;
    float4 v = s[i];
    ushort4 o = {f2u(v.x), f2u(v.y), f2u(v.z), f2u(v.w)};
    d[i] = o;
}

// ---------------- MLP weight pad/convert ----------------
__global__ void k_mpad(const float* __restrict__ W1, const float* __restrict__ W2,
                       u16* __restrict__ W1p, u16* __restrict__ W2p) {
    int t = blockIdx.x * 256 + threadIdx.x;
    if (t < 512 * 32) {
        int o = t >> 5, j = t & 31;
        W1p[t] = (j < 17) ? f2u(W1[o * 17 + j]) : (u16)0;
    } else {
        int t2 = t - 512 * 32;
        int w = t2 >> 9;
        W2p[t2] = (w < 17) ? f2u(W2[t2]) : (u16)0;
    }
}

// ---------------- fused: xin = x + gelu(x) -> XIN bf16; LN_C(xin) -> T bf16 ----------------
__global__ __launch_bounds__(256) void k_xin_lnc(const float* __restrict__ X,
                                                 const float* __restrict__ g,
                                                 const float* __restrict__ bt,
                                                 u16* __restrict__ XIN, u16* __restrict__ T,
                                                 int nrows) {
    int row = blockIdx.x * 4 + (threadIdx.x >> 6);
    if (row >= nrows) return;
    int lane = threadIdx.x & 63;
    const float* xp = X + (size_t)row * Cn + lane * 8;
    float4 v0 = *(const float4*)xp, v1 = *(const float4*)(xp + 4);
    float xv[8] = {v0.x, v0.y, v0.z, v0.w, v1.x, v1.y, v1.z, v1.w};
    bf16x8 xr;
    float vv[8];
#pragma unroll
    for (int k = 0; k < 8; k++) {
        u16 h = f2u(xv[k] + gelu_f(xv[k]));
        xr[k] = (short)h;
        vv[k] = u2f(h);
    }
    *(bf16x8*)(XIN + (size_t)row * Cn + lane * 8) = xr;
    float s = 0.f, q = 0.f;
#pragma unroll
    for (int k = 0; k < 8; k++) { s += vv[k]; q = fmaf(vv[k], vv[k], q); }
#pragma unroll
    for (int o = 32; o; o >>= 1) { s += __shfl_xor(s, o); q += __shfl_xor(q, o); }
    float mean = s * (1.f / Cn);
    float var = q * (1.f / Cn) - mean * mean;
    float inv = 1.f / sqrtf(var + 1e-7f);
    int cb = lane * 8;
    bf16x8 r;
#pragma unroll
    for (int k = 0; k < 8; k++) r[k] = f2u((vv[k] - mean) * inv * g[cb + k] + bt[cb + k]);
    *(bf16x8*)(T + (size_t)row * Cn + cb) = r;
}

// ---------------- LayerNorm over C ----------------
template <int F32IO>
__global__ __launch_bounds__(256) void k_ln_c(const void* __restrict__ Xv,
                                              const float* __restrict__ g,
                                              const float* __restrict__ bt,
                                              void* __restrict__ Ov, int nrows) {
    int row = blockIdx.x * 4 + (threadIdx.x >> 6);
    if (row >= nrows) return;
    int lane = threadIdx.x & 63;
    float vv[8];
    if (F32IO) {
        const float* xp = (const float*)Xv + (size_t)row * Cn + lane * 8;
        float4 v0 = *(const float4*)xp, v1 = *(const float4*)(xp + 4);
        vv[0] = v0.x; vv[1] = v0.y; vv[2] = v0.z; vv[3] = v0.w;
        vv[4] = v1.x; vv[5] = v1.y; vv[6] = v1.z; vv[7] = v1.w;
    } else {
        bf16x8 h = *(const bf16x8*)((const u16*)Xv + (size_t)row * Cn + lane * 8);
#pragma unroll
        for (int k = 0; k < 8; k++) vv[k] = u2f((u16)h[k]);
    }
    float s = 0.f, q = 0.f;
#pragma unroll
    for (int k = 0; k < 8; k++) { s += vv[k]; q = fmaf(vv[k], vv[k], q); }
#pragma unroll
    for (int o = 32; o; o >>= 1) { s += __shfl_xor(s, o); q += __shfl_xor(q, o); }
    float mean = s * (1.f / Cn);
    float var = q * (1.f / Cn) - mean * mean;
    float inv = 1.f / sqrtf(var + 1e-7f);
    int cb = lane * 8;
    if (F32IO) {
        float r[8];
#pragma unroll
        for (int k = 0; k < 8; k++) r[k] = (vv[k] - mean) * inv * g[cb + k] + bt[cb + k];
        float* op = (float*)Ov + (size_t)row * Cn + cb;
        *(float4*)op = make_float4(r[0], r[1], r[2], r[3]);
        *(float4*)(op + 4) = make_float4(r[4], r[5], r[6], r[7]);
    } else {
        bf16x8 r;
#pragma unroll
        for (int k = 0; k < 8; k++) r[k] = f2u((vv[k] - mean) * inv * g[cb + k] + bt[cb + k]);
        *(bf16x8*)((u16*)Ov + (size_t)row * Cn + cb) = r;
    }
}

// ---------------- LayerNorm over J ----------------
__global__ __launch_bounds__(256) void k_ln_j(const u16* __restrict__ X,
                                              const float* __restrict__ g,
                                              const float* __restrict__ bt,
                                              u16* __restrict__ O) {
    int idx = blockIdx.x * 256 + threadIdx.x;
    int b = idx >> 9, c = idx & 511;
    const u16* xp = X + (size_t)b * Vn * Cn + c;
    float v[Vn];
    float s = 0.f;
#pragma unroll
    for (int j = 0; j < Vn; j++) { v[j] = u2f(xp[(size_t)j * Cn]); s += v[j]; }
    float mean = s * (1.f / Vn);
    float q = 0.f;
#pragma unroll
    for (int j = 0; j < Vn; j++) { float d = v[j] - mean; q = fmaf(d, d, q); }
    float inv = 1.f / sqrtf(q * (1.f / Vn) + 1e-7f);
    u16* op = O + (size_t)b * Vn * Cn + c;
#pragma unroll
    for (int j = 0; j < Vn; j++) op[(size_t)j * Cn] = f2u((v[j] - mean) * inv * g[j] + bt[j]);
}

// ---------------- fallback MFMA GEMM (direct-global; used only if CH<16) ----------------
template <int REMAP, int EPI>
__global__ __launch_bounds__(256) void k_gemm(const u16* __restrict__ A, const u16* __restrict__ W,
                                              const float* __restrict__ bias, u16* __restrict__ OutB,
                                              const u16* __restrict__ Res, float* __restrict__ Xf,
                                              int hbase, int shift) {
    constexpr int NT = REMAP ? 6 : 8;
    const int K = 512;
    int wave = threadIdx.x >> 6, lane = threadIdx.x & 63;
    int m0 = blockIdx.x * 128 + wave * 32;
    int nbase = blockIdx.y * (16 * NT);
    int r16 = lane & 15, kq = lane >> 4;
    int ld = REMAP ? (3 << shift) : 512;

    const u16* wp[NT];
    int wrow[NT];
#pragma unroll
    for (int nt = 0; nt < NT; nt++) {
        int n = nbase + nt * 16 + r16;
        int wr;
        if (REMAP) {
            int s = n >> shift, off = n & ((1 << shift) - 1);
            wr = (s << 9) + hbase + off;
        } else wr = n;
        wrow[nt] = wr;
        wp[nt] = W + (size_t)wr * K + kq * 8;
    }
    f32x4 acc[2][NT];
#pragma unroll
    for (int i = 0; i < 2; i++)
#pragma unroll
        for (int nt = 0; nt < NT; nt++) acc[i][nt] = (f32x4){0.f, 0.f, 0.f, 0.f};

    const u16* ap = A + (size_t)(m0 + r16) * K + kq * 8;
    for (int k0 = 0; k0 < K; k0 += 32) {
        bf16x8 a0 = *(const bf16x8*)(ap + k0);
        bf16x8 a1 = *(const bf16x8*)(ap + (size_t)16 * K + k0);
#pragma unroll
        for (int nt = 0; nt < NT; nt++) {
            bf16x8 bf = *(const bf16x8*)(wp[nt] + k0);
            acc[0][nt] = __builtin_amdgcn_mfma_f32_16x16x32_bf16(a0, bf, acc[0][nt], 0, 0, 0);
            acc[1][nt] = __builtin_amdgcn_mfma_f32_16x16x32_bf16(a1, bf, acc[1][nt], 0, 0, 0);
        }
    }
#pragma unroll
    for (int nt = 0; nt < NT; nt++) {
        float bv = bias[wrow[nt]];
        int n = nbase + nt * 16 + r16;
#pragma unroll
        for (int i = 0; i < 2; i++) {
#pragma unroll
            for (int r = 0; r < 4; r++) {
                size_t mb = (size_t)(m0 + i * 16 + kq * 4 + r);
                float v = acc[i][nt][r] + bv;
                if (EPI == 0) OutB[mb * ld + n] = f2u(v);
                else if (EPI == 1) { size_t o = mb * 512 + n; OutB[o] = f2u(v + u2f(Res[o])); }
                else { size_t o = mb * 512 + n; Xf[o] += v; }
            }
        }
    }
}

// ---------------- fast MFMA GEMM: 128x128 tile, BK=64 LDS staged, XCD-chunked panel-major ----------------
template <int EPI, int NY>
__global__ __launch_bounds__(256) void k_gemm2(const u16* __restrict__ A, const u16* __restrict__ W,
                                               const float* __restrict__ bias, u16* __restrict__ OutB,
                                               const u16* __restrict__ Res, float* __restrict__ Xf,
                                               int N) {
    __shared__ u16 As[128 * 64];
    __shared__ u16 Bs[128 * 64];
    const int K = 512;
    int tid = threadIdx.x;
    int wave = tid >> 6, lane = tid & 63;
    int cpx = gridDim.x >> 3;
    int bid = blockIdx.x;
    int swz = (bid & 7) * cpx + (bid >> 3);
    int m0 = (swz / NY) * 128, n0 = (swz % NY) * 128;
    int r16 = lane & 15, kq = lane >> 4;

    int srow = wave << 2;
    int lrow = lane >> 3;
    int lcol = (lane & 7) * 8;

    f32x4 acc[2][8];
#pragma unroll
    for (int i = 0; i < 2; i++)
#pragma unroll
        for (int j = 0; j < 8; j++) acc[i][j] = (f32x4){0.f, 0.f, 0.f, 0.f};

    const u16* aT = As + (wave * 32 + r16) * 64 + kq * 8;
    const u16* bT = Bs + r16 * 64 + kq * 8;

    for (int k0 = 0; k0 < K; k0 += 64) {
#pragma unroll
        for (int i = 0; i < 4; i++) {
            int rows = (srow + i) * 8 + lrow;
            gload16(A + (size_t)(m0 + rows) * K + k0 + lcol, (u16*)As + (srow + i) * 512);
            gload16(W + (size_t)(n0 + rows) * K + k0 + lcol, (u16*)Bs + (srow + i) * 512);
        }
        __syncthreads();
#pragma unroll
        for (int kk = 0; kk < 64; kk += 32) {
            bf16x8 af0 = *(const bf16x8*)(aT + kk);
            bf16x8 af1 = *(const bf16x8*)(aT + 16 * 64 + kk);
#pragma unroll
            for (int nt = 0; nt < 8; nt++) {
                bf16x8 bf = *(const bf16x8*)(bT + nt * 16 * 64 + kk);
                acc[0][nt] = __builtin_amdgcn_mfma_f32_16x16x32_bf16(af0, bf, acc[0][nt], 0, 0, 0);
                acc[1][nt] = __builtin_amdgcn_mfma_f32_16x16x32_bf16(af1, bf, acc[1][nt], 0, 0, 0);
            }
        }
        __syncthreads();
    }

    int mw = m0 + wave * 32;
#pragma unroll
    for (int nt = 0; nt < 8; nt++) {
        int n = n0 + nt * 16 + r16;
        float bv = bias[n];
#pragma unroll
        for (int i = 0; i < 2; i++) {
#pragma unroll
            for (int r = 0; r < 4; r++) {
                size_t mb = (size_t)(mw + i * 16 + kq * 4 + r);
                size_t o = mb * N + n;
                float v = acc[i][nt][r] + bv;
                if (EPI == 0) OutB[o] = f2u(v);
                else if (EPI == 1) OutB[o] = f2u(v + u2f(Res[o]));
                else Xf[o] += v;
            }
        }
    }
}

// ---------------- attention on chunked QKV ----------------
__global__ __launch_bounds__(256) void k_attn(const u16* __restrict__ Y, u16* __restrict__ T,
                                              int shift, int hgbase, int l2ch) {
    int wv = threadIdx.x >> 6, lane = threadIdx.x & 63;
    if (lane >= 34) return;
    int gw = blockIdx.x * 4 + wv;
    int which = (lane >= 17) ? 1 : 0;
    int j = lane - which * 17;
    int pid = gw * 2 + which;
    int b = pid >> l2ch;
    int hl = pid & ((1 << l2ch) - 1);
    int CW = 1 << shift;
    int row3 = 3 << shift;

    const u16* qb = Y + (size_t)(b * Vn + j) * row3 + hl * 32;
    float q[32];
#pragma unroll
    for (int d0 = 0; d0 < 32; d0 += 8) {
        bf16x8 h = *(const bf16x8*)(qb + d0);
#pragma unroll
        for (int d = 0; d < 8; d++) q[d0 + d] = u2f((u16)h[d]);
    }
    float sc[Vn];
    float mx = -1e30f;
#pragma unroll
    for (int kk = 0; kk < Vn; kk++) {
        const u16* kb = Y + (size_t)(b * Vn + kk) * row3 + CW + hl * 32;
        float s = 0.f;
#pragma unroll
        for (int d0 = 0; d0 < 32; d0 += 8) {
            bf16x8 h = *(const bf16x8*)(kb + d0);
#pragma unroll
            for (int d = 0; d < 8; d++) s = fmaf(q[d0 + d], u2f((u16)h[d]), s);
        }
        s *= 0.1767766952966369f;
        sc[kk] = s;
        mx = fmaxf(mx, s);
    }
    float sum = 0.f;
#pragma unroll
    for (int kk = 0; kk < Vn; kk++) { sc[kk] = __expf(sc[kk] - mx); sum += sc[kk]; }
    float inv = 1.f / sum;
    float o[32];
#pragma unroll
    for (int d = 0; d < 32; d++) o[d] = 0.f;
#pragma unroll
    for (int kk = 0; kk < Vn; kk++) {
        const u16* vb = Y + (size_t)(b * Vn + kk) * row3 + 2 * CW + hl * 32;
        float p = sc[kk] * inv;
#pragma unroll
        for (int d0 = 0; d0 < 32; d0 += 8) {
            bf16x8 h = *(const bf16x8*)(vb + d0);
#pragma unroll
            for (int d = 0; d < 8; d++) o[d0 + d] = fmaf(p, u2f((u16)h[d]), o[d0 + d]);
        }
    }
    u16* op = T + (size_t)(b * Vn + j) * Cn + hgbase + hl * 32;
#pragma unroll
    for (int d0 = 0; d0 < 32; d0 += 8) {
        bf16x8 r;
#pragma unroll
        for (int d = 0; d < 8; d++) r[d] = f2u(o[d0 + d]);
        *(bf16x8*)(op + d0) = r;
    }
}

// ---------------- GCN aggregation + fused adds ----------------
template <int MODE>
__global__ __launch_bounds__(256) void k_agg(const u16* __restrict__ Y, const float* __restrict__ Adj,
                                             const u16* __restrict__ aux1, const u16* __restrict__ aux2,
                                             u16* __restrict__ OutB, float* __restrict__ Xf,
                                             int cbase, int shift) {
    __shared__ float adj_s[3][Vn][Vn];
    for (int t = threadIdx.x; t < 3 * Vn * Vn; t += 256) {
        int k = t / (Vn * Vn), r = t - k * Vn * Vn;
        adj_s[k][r / Vn][r % Vn] = Adj[t];
    }
    __syncthreads();
    int CW = 1 << shift;
    int idx = blockIdx.x * 256 + threadIdx.x;
    int b = idx >> shift, co = idx & (CW - 1);
    int c = cbase + co;
    int row3 = 3 << shift;
    float acc[Vn];
#pragma unroll
    for (int w = 0; w < Vn; w++) acc[w] = 0.f;
    const u16* yb = Y + (size_t)b * Vn * row3 + co;
#pragma unroll
    for (int k = 0; k < 3; k++)
#pragma unroll
        for (int v = 0; v < Vn; v++) {
            float y = u2f(yb[(size_t)v * row3 + k * CW]);
#pragma unroll
            for (int w = 0; w < Vn; w++) acc[w] = fmaf(y, adj_s[k][v][w], acc[w]);
        }
    size_t rb = (size_t)(b * Vn) * Cn + c;
#pragma unroll
    for (int w = 0; w < Vn; w++) {
        size_t o = rb + (size_t)w * Cn;
        float val = acc[w] + u2f(aux1[o]) + u2f(aux2[o]);
        if (MODE == 0) OutB[o] = f2u(val);
        else Xf[o] += val;
    }
}

// ---------------- MFMA token-MLP v9 (round-13, packed gelu) ----------------
__global__ __launch_bounds__(512) void k_mlp(const u16* __restrict__ X,
                                             const u16* __restrict__ W1p, const float* __restrict__ B1,
                                             const u16* __restrict__ W2p, const float* __restrict__ B2,
                                             u16* __restrict__ O) {
    __shared__ u16 Xs[256 * 40];
    __shared__ u16 Hs[256 * 40];
    int b = blockIdx.x >> 1;
    int cbase = (blockIdx.x & 1) << 8;
    int tid = threadIdx.x;

    for (int i = tid; i < 256 * 40 / 8; i += 512) ((float4*)Xs)[i] = make_float4(0.f, 0.f, 0.f, 0.f);
    __syncthreads();
    const u16* xb = X + (size_t)b * (Vn * Cn) + cbase;
    for (int i = tid; i < 17 * 256; i += 512) {
        int j = i >> 8, c = i & 255;
        Xs[c * 40 + j] = xb[j * Cn + c];
    }
    __syncthreads();

    int wave = tid >> 6, lane = tid & 63;
    int r16 = lane & 15, kq = lane >> 4;
    int crow = wave * 32;

    bf16x8 xf0 = *(const bf16x8*)(Xs + (crow + r16) * 40 + kq * 8);
    bf16x8 xf1 = *(const bf16x8*)(Xs + (crow + 16 + r16) * 40 + kq * 8);

    f32x4 acc2[2][2];
#pragma unroll
    for (int i = 0; i < 2; i++)
#pragma unroll
        for (int j = 0; j < 2; j++) acc2[i][j] = (f32x4){0.f, 0.f, 0.f, 0.f};

    const u16* hs0 = Hs + (crow + r16) * 40 + kq * 8;
    const u16* w1b = W1p + (r16 << 5) + kq * 8;
    const u16* w2b = W2p + (size_t)r16 * 512 + kq * 8;
    const u16* w2c = W2p + (size_t)16 * 512 + kq * 8;
    const float* b1b = B1 + kq * 4;

#pragma unroll
    for (int s = 0; s < 16; s++) {
        bf16x8 af0 = *(const bf16x8*)(w1b + s * 1024);
        bf16x8 af1 = *(const bf16x8*)(w1b + s * 1024 + 512);
        f32x4 bi0 = *(const f32x4*)(b1b + s * 32);
        f32x4 bi1 = *(const f32x4*)(b1b + s * 32 + 16);
        f32x4 a00 = __builtin_amdgcn_mfma_f32_16x16x32_bf16(af0, xf0, bi0, 0, 0, 0);
        f32x4 a01 = __builtin_amdgcn_mfma_f32_16x16x32_bf16(af0, xf1, bi0, 0, 0, 0);
        f32x4 a10 = __builtin_amdgcn_mfma_f32_16x16x32_bf16(af1, xf0, bi1, 0, 0, 0);
        f32x4 a11 = __builtin_amdgcn_mfma_f32_16x16x32_bf16(af1, xf1, bi1, 0, 0, 0);
#define STORE_H(ACC, NT, OT)                                                             \
        {                                                                                 \
            unsigned g0 = gelu2pk(ACC[0], ACC[1]);                                        \
            unsigned g1 = gelu2pk(ACC[2], ACC[3]);                                        \
            *(uint2*)(Hs + (crow + NT * 16 + r16) * 40 + OT * 16 + kq * 4) =              \
                make_uint2(g0, g1);                                                       \
        }
        STORE_H(a00, 0, 0)
        STORE_H(a01, 1, 0)
        STORE_H(a10, 0, 1)
        STORE_H(a11, 1, 1)
#undef STORE_H
        __builtin_amdgcn_sched_barrier(0);
        bf16x8 h0 = *(const bf16x8*)hs0;
        bf16x8 h1 = *(const bf16x8*)(hs0 + 16 * 40);
        bf16x8 wf0 = *(const bf16x8*)(w2b + s * 32);
        bf16x8 wf1 = *(const bf16x8*)(w2c + s * 32);
        acc2[0][0] = __builtin_amdgcn_mfma_f32_16x16x32_bf16(h0, wf0, acc2[0][0], 0, 0, 0);
        acc2[0][1] = __builtin_amdgcn_mfma_f32_16x16x32_bf16(h0, wf1, acc2[0][1], 0, 0, 0);
        acc2[1][0] = __builtin_amdgcn_mfma_f32_16x16x32_bf16(h1, wf0, acc2[1][0], 0, 0, 0);
        acc2[1][1] = __builtin_amdgcn_mfma_f32_16x16x32_bf16(h1, wf1, acc2[1][1], 0, 0, 0);
    }

    u16* ob = O + (size_t)b * (Vn * Cn) + cbase;
#pragma unroll
    for (int nt = 0; nt < 2; nt++) {
        int cl = crow + nt * 16 + kq * 4;
#pragma unroll
        for (int n2 = 0; n2 < 2; n2++) {
            int w = n2 * 16 + r16;
            if (w < 17) {
                float bb = B2[w];
                f32x4 v = acc2[nt][n2];
                uint2 pk = make_uint2(gelu2pk(v[0] + bb, v[1] + bb),
                                      gelu2pk(v[2] + bb, v[3] + bb));
                *(uint2*)(ob + (size_t)w * Cn + cl) = pk;
            }
        }
    }
}

// ---------------- orchestration ----------------
extern "C" void kernel_launch(void* const* d_in, const int* in_sizes, int n_in,
                              void* d_out, int out_size, void* d_ws, size_t ws_size,
                              hipStream_t stream) {
    (void)in_sizes; (void)n_in; (void)out_size;
    typedef const float* fp;
    fp x_in = (fp)d_in[0];
    fp adj = (fp)d_in[1];
    fp ln1_g = (fp)d_in[2], ln1_b = (fp)d_in[3];
    fp ln2_g = (fp)d_in[4], ln2_b = (fp)d_in[5];
    fp gcn1_w = (fp)d_in[6], gcn1_b = (fp)d_in[7];
    fp gcn2_w = (fp)d_in[8], gcn2_b = (fp)d_in[9];
    fp m1w = (fp)d_in[10], m1b = (fp)d_in[11];
    fp m2w = (fp)d_in[12], m2b = (fp)d_in[13];
    fp aln_g = (fp)d_in[14], aln_b = (fp)d_in[15];
    fp qkv1_w = (fp)d_in[16], qkv1_b = (fp)d_in[17];
    fp p1w = (fp)d_in[18], p1b = (fp)d_in[19];
    fp qkv2_w = (fp)d_in[20], qkv2_b = (fp)d_in[21];
    fp p2w = (fp)d_in[22], p2b = (fp)d_in[23];
    fp tn_g = (fp)d_in[24], tn_b = (fp)d_in[25];

    const size_t NE2 = NE * 2;
    const size_t YCH16 = (size_t)MROWS * 96 * 16 * 2;
    const size_t SZ_QKV3 = (size_t)3 * 1536 * 512;
    const size_t SZ_P3 = (size_t)3 * 512 * 512;
    const size_t MPADL = (size_t)(512 * 32 + 32 * 512);
    const size_t POOLB = (4 * SZ_QKV3 + 2 * SZ_P3 + 3 * MPADL) * 2;
    const size_t WSCR_SZ = (size_t)1536 * 512 * 2;
    const size_t MPAD_SZ = MPADL * 2;

    bool FULLW = false;
    int CH = 0;
    if (3 * NE2 + YCH16 + POOLB + 1024 <= ws_size) { FULLW = true; CH = 16; }
    else {
        for (int ch = 16; ch >= 1; ch >>= 1) {
            size_t need = 3 * NE2 + WSCR_SZ + MPAD_SZ + (size_t)MROWS * 96 * ch * 2 + 1024;
            if (need <= ws_size) { CH = ch; break; }
        }
    }
    if (!CH) {
        k_diag<<<(int)((NE + 255) / 256), 256, 0, stream>>>((float*)d_out, (float)ws_size, (int)NE);
        return;
    }
    const int l2ch = __builtin_ctz(CH);
    const int shift = 5 + l2ch;
    const int NCH = 16 / CH;
    const bool FAST = (CH == 16);

    char* p = (char*)d_ws;
    u16* XIN = (u16*)p;  p += NE2;
    u16* T1 = (u16*)p;   p += NE2;
    u16* T2 = (u16*)p;   p += NE2;
    u16* YCH = (u16*)p;  p += (size_t)MROWS * 96 * CH * 2;
    u16 *WQ1 = nullptr, *WQ2 = nullptr, *WG1 = nullptr, *WG2 = nullptr,
        *WP1 = nullptr, *WP2 = nullptr, *MP1 = nullptr, *MP2 = nullptr, *WSCR = nullptr;
    if (FULLW) {
        WQ1 = (u16*)p; p += SZ_QKV3 * 2;
        WQ2 = (u16*)p; p += SZ_QKV3 * 2;
        WG1 = (u16*)p; p += SZ_QKV3 * 2;
        WG2 = (u16*)p; p += SZ_QKV3 * 2;
        WP1 = (u16*)p; p += SZ_P3 * 2;
        WP2 = (u16*)p; p += SZ_P3 * 2;
        MP1 = (u16*)p; p += 3 * 16384 * 2;
        MP2 = (u16*)p; p += 3 * 16384 * 2;
    } else {
        WSCR = (u16*)p; p += WSCR_SZ;
        MP1 = (u16*)p;  p += 16384 * 2;
        MP2 = (u16*)p;
    }

    float* X = (float*)d_out;
    (void)hipMemcpyAsync(X, x_in, NE * 4, hipMemcpyDeviceToDevice, stream);

    if (FULLW) {
        k_f2b<<<2304, 256, 0, stream>>>((const float4*)qkv1_w, (ushort4*)WQ1, (int)(SZ_QKV3 / 4));
        k_f2b<<<2304, 256, 0, stream>>>((const float4*)qkv2_w, (ushort4*)WQ2, (int)(SZ_QKV3 / 4));
        k_f2b<<<2304, 256, 0, stream>>>((const float4*)gcn1_w, (ushort4*)WG1, (int)(SZ_QKV3 / 4));
        k_f2b<<<2304, 256, 0, stream>>>((const float4*)gcn2_w, (ushort4*)WG2, (int)(SZ_QKV3 / 4));
        k_f2b<<<768, 256, 0, stream>>>((const float4*)p1w, (ushort4*)WP1, (int)(SZ_P3 / 4));
        k_f2b<<<768, 256, 0, stream>>>((const float4*)p2w, (ushort4*)WP2, (int)(SZ_P3 / 4));
        for (int l = 0; l < 3; l++)
            k_mpad<<<128, 256, 0, stream>>>(m1w + (size_t)l * Cn * Vn, m2w + (size_t)l * Vn * Cn,
                                            MP1 + l * 16384, MP2 + l * 16384);
    }

    const int GLN = MROWS / 4;
    const int GBC = Bn * Cn / 256;
    const int GATT = (Bn << l2ch) / 8;
    const int GAGG = (Bn << shift) / 256;
    const dim3 GEMM_C(MROWS / 128, CH);
    const dim3 GEMM_P(MROWS / 128, 4);
    const int CV_QKV = (int)(1536 * 512 / 4 / 256);
    const int CV_P = (int)(512 * 512 / 4 / 256);
    const int GQF = (MROWS / 128) * 12;
    const int GPF = (MROWS / 128) * 4;

    for (int i = 0; i < 3; i++) {
        fp q1w = qkv1_w + (size_t)i * 1536 * 512, q1b = qkv1_b + i * 1536;
        fp q2w = qkv2_w + (size_t)i * 1536 * 512, q2b = qkv2_b + i * 1536;
        fp g1w = gcn1_w + (size_t)i * 1536 * 512, g1b = gcn1_b + i * 1536;
        fp g2w = gcn2_w + (size_t)i * 1536 * 512, g2b = gcn2_b + i * 1536;
        fp pw1 = p1w + (size_t)i * 512 * 512, pb1 = p1b + i * Cn;
        fp pw2 = p2w + (size_t)i * 512 * 512, pb2 = p2b + i * Cn;
        fp alg = aln_g + i * Cn, alb = aln_b + i * Cn;
        fp l1g = ln1_g + i * Vn, l1b_ = ln1_b + i * Vn;
        fp l2g = ln2_g + i * Cn, l2b_ = ln2_b + i * Cn;
        fp w1 = m1w + (size_t)i * Cn * Vn, b1 = m1b + i * Cn;
        fp w2 = m2w + (size_t)i * Vn * Cn, b2 = m2b + i * Vn;

        const u16* wq1p = FULLW ? WQ1 + (size_t)i * 1536 * 512 : WSCR;
        const u16* wq2p = FULLW ? WQ2 + (size_t)i * 1536 * 512 : WSCR;
        const u16* wg1p = FULLW ? WG1 + (size_t)i * 1536 * 512 : WSCR;
        const u16* wg2p = FULLW ? WG2 + (size_t)i * 1536 * 512 : WSCR;
        const u16* wp1p = FULLW ? WP1 + (size_t)i * 512 * 512 : WSCR;
        const u16* wp2p = FULLW ? WP2 + (size_t)i * 512 * 512 : WSCR;
        const u16* mp1 = FULLW ? MP1 + i * 16384 : MP1;
        const u16* mp2 = FULLW ? MP2 + i * 16384 : MP2;

        if (!FULLW) k_mpad<<<128, 256, 0, stream>>>(w1, w2, (u16*)mp1, (u16*)mp2);

        // ---------- gkpc ----------
        k_xin_lnc<<<GLN, 256, 0, stream>>>(X, alg, alb, XIN, T1, MROWS);
        if (!FULLW) k_f2b<<<CV_QKV, 256, 0, stream>>>((const float4*)q1w, (ushort4*)WSCR, 1536 * 512 / 4);
        if (FAST) {
            k_gemm2<0, 12><<<GQF, 256, 0, stream>>>(T1, wq1p, q1b, YCH, nullptr, nullptr, 1536);
            k_attn<<<GATT, 256, 0, stream>>>(YCH, T2, shift, 0, l2ch);
        } else {
            for (int hg = 0; hg < NCH; hg++) {
                k_gemm<1, 0><<<GEMM_C, 256, 0, stream>>>(T1, WSCR, q1b, YCH, nullptr, nullptr, hg << shift, shift);
                k_attn<<<GATT, 256, 0, stream>>>(YCH, T2, shift, hg << shift, l2ch);
            }
        }
        if (!FULLW) k_f2b<<<CV_P, 256, 0, stream>>>((const float4*)pw1, (ushort4*)WSCR, 512 * 512 / 4);
        if (FAST) k_gemm2<1, 4><<<GPF, 256, 0, stream>>>(T2, wp1p, pb1, T1, XIN, nullptr, 512);
        else k_gemm<0, 1><<<GEMM_P, 256, 0, stream>>>(T2, WSCR, pb1, T1, XIN, nullptr, 0, 0);
        k_ln_c<0><<<GLN, 256, 0, stream>>>(T1, alg, alb, T2, MROWS);
        if (!FULLW) k_f2b<<<CV_QKV, 256, 0, stream>>>((const float4*)q2w, (ushort4*)WSCR, 1536 * 512 / 4);
        if (FAST) {
            k_gemm2<0, 12><<<GQF, 256, 0, stream>>>(T2, wq2p, q2b, YCH, nullptr, nullptr, 1536);
            k_attn<<<GATT, 256, 0, stream>>>(YCH, T1, shift, 0, l2ch);
        } else {
            for (int hg = 0; hg < NCH; hg++) {
                k_gemm<1, 0><<<GEMM_C, 256, 0, stream>>>(T2, WSCR, q2b, YCH, nullptr, nullptr, hg << shift, shift);
                k_attn<<<GATT, 256, 0, stream>>>(YCH, T1, shift, hg << shift, l2ch);
            }
        }
        if (!FULLW) k_f2b<<<CV_P, 256, 0, stream>>>((const float4*)pw2, (ushort4*)WSCR, 512 * 512 / 4);
        if (FAST) k_gemm2<2, 4><<<GPF, 256, 0, stream>>>(T1, wp2p, pb2, nullptr, nullptr, X, 512);
        else k_gemm<0, 2><<<GEMM_P, 256, 0, stream>>>(T1, WSCR, pb2, nullptr, nullptr, X, 0, 0);

        // ---------- lrsc ----------
        k_ln_j<<<GBC, 256, 0, stream>>>(XIN, l1g, l1b_, T1);
        k_mlp<<<Bn * 2, 512, 0, stream>>>(T1, mp1, b1, mp2, b2, T2);
        if (!FULLW) k_f2b<<<CV_QKV, 256, 0, stream>>>((const float4*)g1w, (ushort4*)WSCR, 1536 * 512 / 4);
        if (FAST) {
            k_gemm2<0, 12><<<GQF, 256, 0, stream>>>(T1, wg1p, g1b, YCH, nullptr, nullptr, 1536);
            k_agg<0><<<GAGG, 256, 0, stream>>>(YCH, adj, XIN, T2, XIN, nullptr, 0, shift);
        } else {
            for (int cc = 0; cc < NCH; cc++) {
                k_gemm<1, 0><<<GEMM_C, 256, 0, stream>>>(T1, WSCR, g1b, YCH, nullptr, nullptr, cc << shift, shift);
                k_agg<0><<<GAGG, 256, 0, stream>>>(YCH, adj, XIN, T2, XIN, nullptr, cc << shift, shift);
            }
        }
        k_ln_c<0><<<GLN, 256, 0, stream>>>(XIN, l2g, l2b_, T1, MROWS);
        k_mlp<<<Bn * 2, 512, 0, stream>>>(T1, mp1, b1, mp2, b2, T2);
        if (!FULLW) k_f2b<<<CV_QKV, 256, 0, stream>>>((const float4*)g2w, (ushort4*)WSCR, 1536 * 512 / 4);
        if (FAST) {
            k_gemm2<0, 12><<<GQF, 256, 0, stream>>>(T1, wg2p, g2b, YCH, nullptr, nullptr, 1536);
            k_agg<1><<<GAGG, 256, 0, stream>>>(YCH, adj, T1, T2, nullptr, X, 0, shift);
        } else {
            for (int cc = 0; cc < NCH; cc++) {
                k_gemm<1, 0><<<GEMM_C, 256, 0, stream>>>(T1, WSCR, g2b, YCH, nullptr, nullptr, cc << shift, shift);
                k_agg<1><<<GAGG, 256, 0, stream>>>(YCH, adj, T1, T2, nullptr, X, cc << shift, shift);
            }
        }
    }

    k_ln_c<1><<<GLN, 256, 0, stream>>>(X, tn_g, tn_b, X, MROWS);
}

// Round 16
// 3565.439 us; speedup vs baseline: 1.1763x; 1.0409x over previous
//
#include <hip/hip_runtime.h>
#include <hip/hip_bf16.h>
#include <math.h>

#define Bn 2048
#define Vn 17
#define Cn 512
static const size_t NE = (size_t)Bn * Vn * Cn;   // 17,825,792
#define MROWS (Bn * Vn)                           // 34816 = 272 * 128

typedef __attribute__((ext_vector_type(8))) short bf16x8;
typedef __attribute__((ext_vector_type(4))) float f32x4;
typedef __attribute__((ext_vector_type(2))) float f32x2;
typedef unsigned short u16;

__device__ __forceinline__ float u2f(u16 u) { return __uint_as_float(((unsigned)u) << 16); }
__device__ __forceinline__ u16 f2u(float f) {
    unsigned u = __float_as_uint(f);
    return (u16)((u + 0x7fffu + ((u >> 16) & 1u)) >> 16);   // RNE fp32->bf16
}
__device__ __forceinline__ float gelu_f(float x) {
    return 0.5f * x * (1.0f + erff(x * 0.70710678118654752f));
}
__device__ __forceinline__ float exp2f_fast(float b) {
#if __has_builtin(__builtin_amdgcn_exp2f)
    return __builtin_amdgcn_exp2f(b);
#else
    return __expf(b * 0.69314718056f);
#endif
}
// tanh-form gelu: x * sigmoid(x*(1.5957691 + 0.0713548 x^2)); exp2-folded. max abs err ~1e-3
__device__ __forceinline__ float gelu_fast(float x) {
    float b = x * fmaf(x * x, -0.10294348f, -2.30220820f);
    return x * __builtin_amdgcn_rcpf(1.0f + exp2f_fast(b));
}
__device__ __forceinline__ unsigned pk2(float lo, float hi) {
    __hip_bfloat162 h = __float22bfloat162_rn(make_float2(lo, hi));
    unsigned r;
    __builtin_memcpy(&r, &h, 4);
    return r;
}
// two gelus via packed fp32 VALU; returns bf16x2 packed word
__device__ __forceinline__ unsigned gelu2pk(float x0, float x1) {
    f32x2 x = {x0, x1};
    f32x2 xx = x * x;
    f32x2 t = xx * (f32x2){-0.10294348f, -0.10294348f} +
              (f32x2){-2.30220820f, -2.30220820f};
    f32x2 b = x * t;
    f32x2 e = {exp2f_fast(b[0]), exp2f_fast(b[1])};
    f32x2 d = e + (f32x2){1.0f, 1.0f};
    f32x2 r = {__builtin_amdgcn_rcpf(d[0]), __builtin_amdgcn_rcpf(d[1])};
    f32x2 g = x * r;
    return pk2(g[0], g[1]);
}
__device__ __forceinline__ void gload16(const u16* g, u16* l) {
    __builtin_amdgcn_global_load_lds((const __attribute__((address_space(1))) void*)g,
                                     (__attribute__((address_space(3))) void*)l, 16, 0, 0);
}

// ---------------- diagnostic ----------------
__global__ void k_diag(float* __restrict__ o, float v, int n) {
    int i = blockIdx.x * 256 + threadIdx.x;
    if (i < n) o[i] = v;
}

// ---------------- fp32 -> bf16 weight conversion ----------------
__global__ void k_f2b(const float4* __restrict__ s, ushort4* __restrict__ d, int n4) {
    int i = blockIdx.x * 256 + threadIdx.x;
    if (i >= n4) return;
    float4 v = s[i];
    ushort4 o = {f2u(v.x), f2u(v.y), f2u(v.z), f2u(v.w)};
    d[i] = o;
}

// ---------------- MLP weight pad/convert ----------------
__global__ void k_mpad(const float* __restrict__ W1, const float* __restrict__ W2,
                       u16* __restrict__ W1p, u16* __restrict__ W2p) {
    int t = blockIdx.x * 256 + threadIdx.x;
    if (t < 512 * 32) {
        int o = t >> 5, j = t & 31;
        W1p[t] = (j < 17) ? f2u(W1[o * 17 + j]) : (u16)0;
    } else {
        int t2 = t - 512 * 32;
        int w = t2 >> 9;
        W2p[t2] = (w < 17) ? f2u(W2[t2]) : (u16)0;
    }
}

// ---------------- fused: xin = x + gelu(x) -> XIN bf16; LN_C(xin) -> T bf16 ----------------
__global__ __launch_bounds__(256) void k_xin_lnc(const float* __restrict__ X,
                                                 const float* __restrict__ g,
                                                 const float* __restrict__ bt,
                                                 u16* __restrict__ XIN, u16* __restrict__ T,
                                                 int nrows) {
    int row = blockIdx.x * 4 + (threadIdx.x >> 6);
    if (row >= nrows) return;
    int lane = threadIdx.x & 63;
    const float* xp = X + (size_t)row * Cn + lane * 8;
    float4 v0 = *(const float4*)xp, v1 = *(const float4*)(xp + 4);
    float xv[8] = {v0.x, v0.y, v0.z, v0.w, v1.x, v1.y, v1.z, v1.w};
    bf16x8 xr;
    float vv[8];
#pragma unroll
    for (int k = 0; k < 8; k++) {
        u16 h = f2u(xv[k] + gelu_f(xv[k]));
        xr[k] = (short)h;
        vv[k] = u2f(h);
    }
    *(bf16x8*)(XIN + (size_t)row * Cn + lane * 8) = xr;
    float s = 0.f, q = 0.f;
#pragma unroll
    for (int k = 0; k < 8; k++) { s += vv[k]; q = fmaf(vv[k], vv[k], q); }
#pragma unroll
    for (int o = 32; o; o >>= 1) { s += __shfl_xor(s, o); q += __shfl_xor(q, o); }
    float mean = s * (1.f / Cn);
    float var = q * (1.f / Cn) - mean * mean;
    float inv = 1.f / sqrtf(var + 1e-7f);
    int cb = lane * 8;
    bf16x8 r;
#pragma unroll
    for (int k = 0; k < 8; k++) r[k] = f2u((vv[k] - mean) * inv * g[cb + k] + bt[cb + k]);
    *(bf16x8*)(T + (size_t)row * Cn + cb) = r;
}

// ---------------- LayerNorm over C ----------------
template <int F32IO>
__global__ __launch_bounds__(256) void k_ln_c(const void* __restrict__ Xv,
                                              const float* __restrict__ g,
                                              const float* __restrict__ bt,
                                              void* __restrict__ Ov, int nrows) {
    int row = blockIdx.x * 4 + (threadIdx.x >> 6);
    if (row >= nrows) return;
    int lane = threadIdx.x & 63;
    float vv[8];
    if (F32IO) {
        const float* xp = (const float*)Xv + (size_t)row * Cn + lane * 8;
        float4 v0 = *(const float4*)xp, v1 = *(const float4*)(xp + 4);
        vv[0] = v0.x; vv[1] = v0.y; vv[2] = v0.z; vv[3] = v0.w;
        vv[4] = v1.x; vv[5] = v1.y; vv[6] = v1.z; vv[7] = v1.w;
    } else {
        bf16x8 h = *(const bf16x8*)((const u16*)Xv + (size_t)row * Cn + lane * 8);
#pragma unroll
        for (int k = 0; k < 8; k++) vv[k] = u2f((u16)h[k]);
    }
    float s = 0.f, q = 0.f;
#pragma unroll
    for (int k = 0; k < 8; k++) { s += vv[k]; q = fmaf(vv[k], vv[k], q); }
#pragma unroll
    for (int o = 32; o; o >>= 1) { s += __shfl_xor(s, o); q += __shfl_xor(q, o); }
    float mean = s * (1.f / Cn);
    float var = q * (1.f / Cn) - mean * mean;
    float inv = 1.f / sqrtf(var + 1e-7f);
    int cb = lane * 8;
    if (F32IO) {
        float r[8];
#pragma unroll
        for (int k = 0; k < 8; k++) r[k] = (vv[k] - mean) * inv * g[cb + k] + bt[cb + k];
        float* op = (float*)Ov + (size_t)row * Cn + cb;
        *(float4*)op = make_float4(r[0], r[1], r[2], r[3]);
        *(float4*)(op + 4) = make_float4(r[4], r[5], r[6], r[7]);
    } else {
        bf16x8 r;
#pragma unroll
        for (int k = 0; k < 8; k++) r[k] = f2u((vv[k] - mean) * inv * g[cb + k] + bt[cb + k]);
        *(bf16x8*)((u16*)Ov + (size_t)row * Cn + cb) = r;
    }
}

// ---------------- LayerNorm over J ----------------
__global__ __launch_bounds__(256) void k_ln_j(const u16* __restrict__ X,
                                              const float* __restrict__ g,
                                              const float* __restrict__ bt,
                                              u16* __restrict__ O) {
    int idx = blockIdx.x * 256 + threadIdx.x;
    int b = idx >> 9, c = idx & 511;
    const u16* xp = X + (size_t)b * Vn * Cn + c;
    float v[Vn];
    float s = 0.f;
#pragma unroll
    for (int j = 0; j < Vn; j++) { v[j] = u2f(xp[(size_t)j * Cn]); s += v[j]; }
    float mean = s * (1.f / Vn);
    float q = 0.f;
#pragma unroll
    for (int j = 0; j < Vn; j++) { float d = v[j] - mean; q = fmaf(d, d, q); }
    float inv = 1.f / sqrtf(q * (1.f / Vn) + 1e-7f);
    u16* op = O + (size_t)b * Vn * Cn + c;
#pragma unroll
    for (int j = 0; j < Vn; j++) op[(size_t)j * Cn] = f2u((v[j] - mean) * inv * g[j] + bt[j]);
}

// ---------------- fallback MFMA GEMM (direct-global; used only if CH<16) ----------------
template <int REMAP, int EPI>
__global__ __launch_bounds__(256) void k_gemm(const u16* __restrict__ A, const u16* __restrict__ W,
                                              const float* __restrict__ bias, u16* __restrict__ OutB,
                                              const u16* __restrict__ Res, float* __restrict__ Xf,
                                              int hbase, int shift) {
    constexpr int NT = REMAP ? 6 : 8;
    const int K = 512;
    int wave = threadIdx.x >> 6, lane = threadIdx.x & 63;
    int m0 = blockIdx.x * 128 + wave * 32;
    int nbase = blockIdx.y * (16 * NT);
    int r16 = lane & 15, kq = lane >> 4;
    int ld = REMAP ? (3 << shift) : 512;

    const u16* wp[NT];
    int wrow[NT];
#pragma unroll
    for (int nt = 0; nt < NT; nt++) {
        int n = nbase + nt * 16 + r16;
        int wr;
        if (REMAP) {
            int s = n >> shift, off = n & ((1 << shift) - 1);
            wr = (s << 9) + hbase + off;
        } else wr = n;
        wrow[nt] = wr;
        wp[nt] = W + (size_t)wr * K + kq * 8;
    }
    f32x4 acc[2][NT];
#pragma unroll
    for (int i = 0; i < 2; i++)
#pragma unroll
        for (int nt = 0; nt < NT; nt++) acc[i][nt] = (f32x4){0.f, 0.f, 0.f, 0.f};

    const u16* ap = A + (size_t)(m0 + r16) * K + kq * 8;
    for (int k0 = 0; k0 < K; k0 += 32) {
        bf16x8 a0 = *(const bf16x8*)(ap + k0);
        bf16x8 a1 = *(const bf16x8*)(ap + (size_t)16 * K + k0);
#pragma unroll
        for (int nt = 0; nt < NT; nt++) {
            bf16x8 bf = *(const bf16x8*)(wp[nt] + k0);
            acc[0][nt] = __builtin_amdgcn_mfma_f32_16x16x32_bf16(a0, bf, acc[0][nt], 0, 0, 0);
            acc[1][nt] = __builtin_amdgcn_mfma_f32_16x16x32_bf16(a1, bf, acc[1][nt], 0, 0, 0);
        }
    }
#pragma unroll
    for (int nt = 0; nt < NT; nt++) {
        float bv = bias[wrow[nt]];
        int n = nbase + nt * 16 + r16;
#pragma unroll
        for (int i = 0; i < 2; i++) {
#pragma unroll
            for (int r = 0; r < 4; r++) {
                size_t mb = (size_t)(m0 + i * 16 + kq * 4 + r);
                float v = acc[i][nt][r] + bv;
                if (EPI == 0) OutB[mb * ld + n] = f2u(v);
                else if (EPI == 1) { size_t o = mb * 512 + n; OutB[o] = f2u(v + u2f(Res[o])); }
                else { size_t o = mb * 512 + n; Xf[o] += v; }
            }
        }
    }
}

// ---------------- fast MFMA GEMM: 128x128 tile, BK=64 LDS staged, XCD-chunked panel-major ----------------
template <int EPI, int NY>
__global__ __launch_bounds__(256) void k_gemm2(const u16* __restrict__ A, const u16* __restrict__ W,
                                               const float* __restrict__ bias, u16* __restrict__ OutB,
                                               const u16* __restrict__ Res, float* __restrict__ Xf,
                                               int N) {
    __shared__ u16 As[128 * 64];
    __shared__ u16 Bs[128 * 64];
    const int K = 512;
    int tid = threadIdx.x;
    int wave = tid >> 6, lane = tid & 63;
    int cpx = gridDim.x >> 3;
    int bid = blockIdx.x;
    int swz = (bid & 7) * cpx + (bid >> 3);
    int m0 = (swz / NY) * 128, n0 = (swz % NY) * 128;
    int r16 = lane & 15, kq = lane >> 4;

    int srow = wave << 2;
    int lrow = lane >> 3;
    int lcol = (lane & 7) * 8;

    f32x4 acc[2][8];
#pragma unroll
    for (int i = 0; i < 2; i++)
#pragma unroll
        for (int j = 0; j < 8; j++) acc[i][j] = (f32x4){0.f, 0.f, 0.f, 0.f};

    const u16* aT = As + (wave * 32 + r16) * 64 + kq * 8;
    const u16* bT = Bs + r16 * 64 + kq * 8;

    for (int k0 = 0; k0 < K; k0 += 64) {
#pragma unroll
        for (int i = 0; i < 4; i++) {
            int rows = (srow + i) * 8 + lrow;
            gload16(A + (size_t)(m0 + rows) * K + k0 + lcol, (u16*)As + (srow + i) * 512);
            gload16(W + (size_t)(n0 + rows) * K + k0 + lcol, (u16*)Bs + (srow + i) * 512);
        }
        __syncthreads();
#pragma unroll
        for (int kk = 0; kk < 64; kk += 32) {
            bf16x8 af0 = *(const bf16x8*)(aT + kk);
            bf16x8 af1 = *(const bf16x8*)(aT + 16 * 64 + kk);
#pragma unroll
            for (int nt = 0; nt < 8; nt++) {
                bf16x8 bf = *(const bf16x8*)(bT + nt * 16 * 64 + kk);
                acc[0][nt] = __builtin_amdgcn_mfma_f32_16x16x32_bf16(af0, bf, acc[0][nt], 0, 0, 0);
                acc[1][nt] = __builtin_amdgcn_mfma_f32_16x16x32_bf16(af1, bf, acc[1][nt], 0, 0, 0);
            }
        }
        __syncthreads();
    }

    int mw = m0 + wave * 32;
#pragma unroll
    for (int nt = 0; nt < 8; nt++) {
        int n = n0 + nt * 16 + r16;
        float bv = bias[n];
#pragma unroll
        for (int i = 0; i < 2; i++) {
#pragma unroll
            for (int r = 0; r < 4; r++) {
                size_t mb = (size_t)(mw + i * 16 + kq * 4 + r);
                size_t o = mb * N + n;
                float v = acc[i][nt][r] + bv;
                if (EPI == 0) OutB[o] = f2u(v);
                else if (EPI == 1) OutB[o] = f2u(v + u2f(Res[o]));
                else Xf[o] += v;
            }
        }
    }
}

// ---------------- attention on chunked QKV: 3 (b,h) pairs per wave (51/64 lanes) ----------------
__global__ __launch_bounds__(256) void k_attn(const u16* __restrict__ Y, u16* __restrict__ T,
                                              int shift, int hgbase, int l2ch, int npid) {
    int wv = threadIdx.x >> 6, lane = threadIdx.x & 63;
    if (lane >= 51) return;
    int which = (lane >= 34) ? 2 : ((lane >= 17) ? 1 : 0);
    int j = lane - which * 17;
    int pid = (blockIdx.x * 4 + wv) * 3 + which;
    if (pid >= npid) return;
    int b = pid >> l2ch;
    int hl = pid & ((1 << l2ch) - 1);
    int CW = 1 << shift;
    int row3 = 3 << shift;

    const u16* qb = Y + (size_t)(b * Vn + j) * row3 + hl * 32;
    float q[32];
#pragma unroll
    for (int d0 = 0; d0 < 32; d0 += 8) {
        bf16x8 h = *(const bf16x8*)(qb + d0);
#pragma unroll
        for (int d = 0; d < 8; d++) q[d0 + d] = u2f((u16)h[d]);
    }
    float sc[Vn];
    float mx = -1e30f;
#pragma unroll
    for (int kk = 0; kk < Vn; kk++) {
        const u16* kb = Y + (size_t)(b * Vn + kk) * row3 + CW + hl * 32;
        float s = 0.f;
#pragma unroll
        for (int d0 = 0; d0 < 32; d0 += 8) {
            bf16x8 h = *(const bf16x8*)(kb + d0);
#pragma unroll
            for (int d = 0; d < 8; d++) s = fmaf(q[d0 + d], u2f((u16)h[d]), s);
        }
        s *= 0.1767766952966369f;
        sc[kk] = s;
        mx = fmaxf(mx, s);
    }
    float sum = 0.f;
#pragma unroll
    for (int kk = 0; kk < Vn; kk++) { sc[kk] = __expf(sc[kk] - mx); sum += sc[kk]; }
    float inv = 1.f / sum;
    float o[32];
#pragma unroll
    for (int d = 0; d < 32; d++) o[d] = 0.f;
#pragma unroll
    for (int kk = 0; kk < Vn; kk++) {
        const u16* vb = Y + (size_t)(b * Vn + kk) * row3 + 2 * CW + hl * 32;
        float p = sc[kk] * inv;
#pragma unroll
        for (int d0 = 0; d0 < 32; d0 += 8) {
            bf16x8 h = *(const bf16x8*)(vb + d0);
#pragma unroll
            for (int d = 0; d < 8; d++) o[d0 + d] = fmaf(p, u2f((u16)h[d]), o[d0 + d]);
        }
    }
    u16* op = T + (size_t)(b * Vn + j) * Cn + hgbase + hl * 32;
#pragma unroll
    for (int d0 = 0; d0 < 32; d0 += 8) {
        bf16x8 r;
#pragma unroll
        for (int d = 0; d < 8; d++) r[d] = f2u(o[d0 + d]);
        *(bf16x8*)(op + d0) = r;
    }
}

// ---------------- GCN aggregation + fused adds ----------------
template <int MODE>
__global__ __launch_bounds__(256) void k_agg(const u16* __restrict__ Y, const float* __restrict__ Adj,
                                             const u16* __restrict__ aux1, const u16* __restrict__ aux2,
                                             u16* __restrict__ OutB, float* __restrict__ Xf,
                                             int cbase, int shift) {
    __shared__ float adj_s[3][Vn][Vn];
    for (int t = threadIdx.x; t < 3 * Vn * Vn; t += 256) {
        int k = t / (Vn * Vn), r = t - k * Vn * Vn;
        adj_s[k][r / Vn][r % Vn] = Adj[t];
    }
    __syncthreads();
    int CW = 1 << shift;
    int idx = blockIdx.x * 256 + threadIdx.x;
    int b = idx >> shift, co = idx & (CW - 1);
    int c = cbase + co;
    int row3 = 3 << shift;
    float acc[Vn];
#pragma unroll
    for (int w = 0; w < Vn; w++) acc[w] = 0.f;
    const u16* yb = Y + (size_t)b * Vn * row3 + co;
#pragma unroll
    for (int k = 0; k < 3; k++)
#pragma unroll
        for (int v = 0; v < Vn; v++) {
            float y = u2f(yb[(size_t)v * row3 + k * CW]);
#pragma unroll
            for (int w = 0; w < Vn; w++) acc[w] = fmaf(y, adj_s[k][v][w], acc[w]);
        }
    size_t rb = (size_t)(b * Vn) * Cn + c;
#pragma unroll
    for (int w = 0; w < Vn; w++) {
        size_t o = rb + (size_t)w * Cn;
        float val = acc[w] + u2f(aux1[o]) + u2f(aux2[o]);
        if (MODE == 0) OutB[o] = f2u(val);
        else Xf[o] += val;
    }
}

// ---------------- MFMA token-MLP v10: packed gelu + vectorized row-major Xs staging ----------------
__global__ __launch_bounds__(512) void k_mlp(const u16* __restrict__ X,
                                             const u16* __restrict__ W1p, const float* __restrict__ B1,
                                             const u16* __restrict__ W2p, const float* __restrict__ B2,
                                             u16* __restrict__ O) {
    __shared__ u16 Xs[32 * 256];   // [j][c_local] row-major; rows 17..31 zero (16 KB)
    __shared__ u16 Hs[256 * 40];   // [c_local][o_strip 0..31, pad 40] (20 KB) -> total 36 KB
    int b = blockIdx.x >> 1;
    int cbase = (blockIdx.x & 1) << 8;
    int tid = threadIdx.x;

    // zero only the j-pad rows (17..31): 15*256 u16 = 480 float4s
    for (int i = tid; i < 480; i += 512) ((float4*)(Xs + 17 * 256))[i] = make_float4(0.f, 0.f, 0.f, 0.f);
    // coalesced vector staging: 544 bf16x8 copies
    const u16* xb = X + (size_t)b * (Vn * Cn) + cbase;
    for (int i = tid; i < 17 * 32; i += 512) {
        int j = i >> 5, c8 = (i & 31) * 8;
        *(bf16x8*)(Xs + j * 256 + c8) = *(const bf16x8*)(xb + j * Cn + c8);
    }
    __syncthreads();

    int wave = tid >> 6, lane = tid & 63;
    int r16 = lane & 15, kq = lane >> 4;
    int crow = wave * 32;

    // hoisted one-time gather of GEMM1 B-fragments from row-major Xs
    bf16x8 xf0, xf1;
#pragma unroll
    for (int e = 0; e < 8; e++) {
        xf0[e] = (short)Xs[(kq * 8 + e) * 256 + crow + r16];
        xf1[e] = (short)Xs[(kq * 8 + e) * 256 + crow + 16 + r16];
    }

    f32x4 acc2[2][2];
#pragma unroll
    for (int i = 0; i < 2; i++)
#pragma unroll
        for (int j = 0; j < 2; j++) acc2[i][j] = (f32x4){0.f, 0.f, 0.f, 0.f};

    const u16* hs0 = Hs + (crow + r16) * 40 + kq * 8;
    const u16* w1b = W1p + (r16 << 5) + kq * 8;
    const u16* w2b = W2p + (size_t)r16 * 512 + kq * 8;
    const u16* w2c = W2p + (size_t)16 * 512 + kq * 8;
    const float* b1b = B1 + kq * 4;

#pragma unroll
    for (int s = 0; s < 16; s++) {
        bf16x8 af0 = *(const bf16x8*)(w1b + s * 1024);
        bf16x8 af1 = *(const bf16x8*)(w1b + s * 1024 + 512);
        f32x4 bi0 = *(const f32x4*)(b1b + s * 32);
        f32x4 bi1 = *(const f32x4*)(b1b + s * 32 + 16);
        f32x4 a00 = __builtin_amdgcn_mfma_f32_16x16x32_bf16(af0, xf0, bi0, 0, 0, 0);
        f32x4 a01 = __builtin_amdgcn_mfma_f32_16x16x32_bf16(af0, xf1, bi0, 0, 0, 0);
        f32x4 a10 = __builtin_amdgcn_mfma_f32_16x16x32_bf16(af1, xf0, bi1, 0, 0, 0);
        f32x4 a11 = __builtin_amdgcn_mfma_f32_16x16x32_bf16(af1, xf1, bi1, 0, 0, 0);
#define STORE_H(ACC, NT, OT)                                                             \
        {                                                                                 \
            unsigned g0 = gelu2pk(ACC[0], ACC[1]);                                        \
            unsigned g1 = gelu2pk(ACC[2], ACC[3]);                                        \
            *(uint2*)(Hs + (crow + NT * 16 + r16) * 40 + OT * 16 + kq * 4) =              \
                make_uint2(g0, g1);                                                       \
        }
        STORE_H(a00, 0, 0)
        STORE_H(a01, 1, 0)
        STORE_H(a10, 0, 1)
        STORE_H(a11, 1, 1)
#undef STORE_H
        __builtin_amdgcn_sched_barrier(0);
        bf16x8 h0 = *(const bf16x8*)hs0;
        bf16x8 h1 = *(const bf16x8*)(hs0 + 16 * 40);
        bf16x8 wf0 = *(const bf16x8*)(w2b + s * 32);
        bf16x8 wf1 = *(const bf16x8*)(w2c + s * 32);
        acc2[0][0] = __builtin_amdgcn_mfma_f32_16x16x32_bf16(h0, wf0, acc2[0][0], 0, 0, 0);
        acc2[0][1] = __builtin_amdgcn_mfma_f32_16x16x32_bf16(h0, wf1, acc2[0][1], 0, 0, 0);
        acc2[1][0] = __builtin_amdgcn_mfma_f32_16x16x32_bf16(h1, wf0, acc2[1][0], 0, 0, 0);
        acc2[1][1] = __builtin_amdgcn_mfma_f32_16x16x32_bf16(h1, wf1, acc2[1][1], 0, 0, 0);
    }

    u16* ob = O + (size_t)b * (Vn * Cn) + cbase;
#pragma unroll
    for (int nt = 0; nt < 2; nt++) {
        int cl = crow + nt * 16 + kq * 4;
#pragma unroll
        for (int n2 = 0; n2 < 2; n2++) {
            int w = n2 * 16 + r16;
            if (w < 17) {
                float bb = B2[w];
                f32x4 v = acc2[nt][n2];
                uint2 pk = make_uint2(gelu2pk(v[0] + bb, v[1] + bb),
                                      gelu2pk(v[2] + bb, v[3] + bb));
                *(uint2*)(ob + (size_t)w * Cn + cl) = pk;
            }
        }
    }
}

// ---------------- orchestration ----------------
extern "C" void kernel_launch(void* const* d_in, const int* in_sizes, int n_in,
                              void* d_out, int out_size, void* d_ws, size_t ws_size,
                              hipStream_t stream) {
    (void)in_sizes; (void)n_in; (void)out_size;
    typedef const float* fp;
    fp x_in = (fp)d_in[0];
    fp adj = (fp)d_in[1];
    fp ln1_g = (fp)d_in[2], ln1_b = (fp)d_in[3];
    fp ln2_g = (fp)d_in[4], ln2_b = (fp)d_in[5];
    fp gcn1_w = (fp)d_in[6], gcn1_b = (fp)d_in[7];
    fp gcn2_w = (fp)d_in[8], gcn2_b = (fp)d_in[9];
    fp m1w = (fp)d_in[10], m1b = (fp)d_in[11];
    fp m2w = (fp)d_in[12], m2b = (fp)d_in[13];
    fp aln_g = (fp)d_in[14], aln_b = (fp)d_in[15];
    fp qkv1_w = (fp)d_in[16], qkv1_b = (fp)d_in[17];
    fp p1w = (fp)d_in[18], p1b = (fp)d_in[19];
    fp qkv2_w = (fp)d_in[20], qkv2_b = (fp)d_in[21];
    fp p2w = (fp)d_in[22], p2b = (fp)d_in[23];
    fp tn_g = (fp)d_in[24], tn_b = (fp)d_in[25];

    const size_t NE2 = NE * 2;
    const size_t YCH16 = (size_t)MROWS * 96 * 16 * 2;
    const size_t SZ_QKV3 = (size_t)3 * 1536 * 512;
    const size_t SZ_P3 = (size_t)3 * 512 * 512;
    const size_t MPADL = (size_t)(512 * 32 + 32 * 512);
    const size_t POOLB = (4 * SZ_QKV3 + 2 * SZ_P3 + 3 * MPADL) * 2;
    const size_t WSCR_SZ = (size_t)1536 * 512 * 2;
    const size_t MPAD_SZ = MPADL * 2;

    bool FULLW = false;
    int CH = 0;
    if (3 * NE2 + YCH16 + POOLB + 1024 <= ws_size) { FULLW = true; CH = 16; }
    else {
        for (int ch = 16; ch >= 1; ch >>= 1) {
            size_t need = 3 * NE2 + WSCR_SZ + MPAD_SZ + (size_t)MROWS * 96 * ch * 2 + 1024;
            if (need <= ws_size) { CH = ch; break; }
        }
    }
    if (!CH) {
        k_diag<<<(int)((NE + 255) / 256), 256, 0, stream>>>((float*)d_out, (float)ws_size, (int)NE);
        return;
    }
    const int l2ch = __builtin_ctz(CH);
    const int shift = 5 + l2ch;
    const int NCH = 16 / CH;
    const bool FAST = (CH == 16);

    char* p = (char*)d_ws;
    u16* XIN = (u16*)p;  p += NE2;
    u16* T1 = (u16*)p;   p += NE2;
    u16* T2 = (u16*)p;   p += NE2;
    u16* YCH = (u16*)p;  p += (size_t)MROWS * 96 * CH * 2;
    u16 *WQ1 = nullptr, *WQ2 = nullptr, *WG1 = nullptr, *WG2 = nullptr,
        *WP1 = nullptr, *WP2 = nullptr, *MP1 = nullptr, *MP2 = nullptr, *WSCR = nullptr;
    if (FULLW) {
        WQ1 = (u16*)p; p += SZ_QKV3 * 2;
        WQ2 = (u16*)p; p += SZ_QKV3 * 2;
        WG1 = (u16*)p; p += SZ_QKV3 * 2;
        WG2 = (u16*)p; p += SZ_QKV3 * 2;
        WP1 = (u16*)p; p += SZ_P3 * 2;
        WP2 = (u16*)p; p += SZ_P3 * 2;
        MP1 = (u16*)p; p += 3 * 16384 * 2;
        MP2 = (u16*)p; p += 3 * 16384 * 2;
    } else {
        WSCR = (u16*)p; p += WSCR_SZ;
        MP1 = (u16*)p;  p += 16384 * 2;
        MP2 = (u16*)p;
    }

    float* X = (float*)d_out;
    (void)hipMemcpyAsync(X, x_in, NE * 4, hipMemcpyDeviceToDevice, stream);

    if (FULLW) {
        k_f2b<<<2304, 256, 0, stream>>>((const float4*)qkv1_w, (ushort4*)WQ1, (int)(SZ_QKV3 / 4));
        k_f2b<<<2304, 256, 0, stream>>>((const float4*)qkv2_w, (ushort4*)WQ2, (int)(SZ_QKV3 / 4));
        k_f2b<<<2304, 256, 0, stream>>>((const float4*)gcn1_w, (ushort4*)WG1, (int)(SZ_QKV3 / 4));
        k_f2b<<<2304, 256, 0, stream>>>((const float4*)gcn2_w, (ushort4*)WG2, (int)(SZ_QKV3 / 4));
        k_f2b<<<768, 256, 0, stream>>>((const float4*)p1w, (ushort4*)WP1, (int)(SZ_P3 / 4));
        k_f2b<<<768, 256, 0, stream>>>((const float4*)p2w, (ushort4*)WP2, (int)(SZ_P3 / 4));
        for (int l = 0; l < 3; l++)
            k_mpad<<<128, 256, 0, stream>>>(m1w + (size_t)l * Cn * Vn, m2w + (size_t)l * Vn * Cn,
                                            MP1 + l * 16384, MP2 + l * 16384);
    }

    const int GLN = MROWS / 4;
    const int GBC = Bn * Cn / 256;
    const int NPID = Bn << l2ch;                  // total (b,h) units
    const int GATT = (NPID + 11) / 12;            // 12 units per 256-thr block (3/wave)
    const int GAGG = (Bn << shift) / 256;
    const dim3 GEMM_C(MROWS / 128, CH);
    const dim3 GEMM_P(MROWS / 128, 4);
    const int CV_QKV = (int)(1536 * 512 / 4 / 256);
    const int CV_P = (int)(512 * 512 / 4 / 256);
    const int GQF = (MROWS / 128) * 12;
    const int GPF = (MROWS / 128) * 4;

    for (int i = 0; i < 3; i++) {
        fp q1w = qkv1_w + (size_t)i * 1536 * 512, q1b = qkv1_b + i * 1536;
        fp q2w = qkv2_w + (size_t)i * 1536 * 512, q2b = qkv2_b + i * 1536;
        fp g1w = gcn1_w + (size_t)i * 1536 * 512, g1b = gcn1_b + i * 1536;
        fp g2w = gcn2_w + (size_t)i * 1536 * 512, g2b = gcn2_b + i * 1536;
        fp pw1 = p1w + (size_t)i * 512 * 512, pb1 = p1b + i * Cn;
        fp pw2 = p2w + (size_t)i * 512 * 512, pb2 = p2b + i * Cn;
        fp alg = aln_g + i * Cn, alb = aln_b + i * Cn;
        fp l1g = ln1_g + i * Vn, l1b_ = ln1_b + i * Vn;
        fp l2g = ln2_g + i * Cn, l2b_ = ln2_b + i * Cn;
        fp w1 = m1w + (size_t)i * Cn * Vn, b1 = m1b + i * Cn;
        fp w2 = m2w + (size_t)i * Vn * Cn, b2 = m2b + i * Vn;

        const u16* wq1p = FULLW ? WQ1 + (size_t)i * 1536 * 512 : WSCR;
        const u16* wq2p = FULLW ? WQ2 + (size_t)i * 1536 * 512 : WSCR;
        const u16* wg1p = FULLW ? WG1 + (size_t)i * 1536 * 512 : WSCR;
        const u16* wg2p = FULLW ? WG2 + (size_t)i * 1536 * 512 : WSCR;
        const u16* wp1p = FULLW ? WP1 + (size_t)i * 512 * 512 : WSCR;
        const u16* wp2p = FULLW ? WP2 + (size_t)i * 512 * 512 : WSCR;
        const u16* mp1 = FULLW ? MP1 + i * 16384 : MP1;
        const u16* mp2 = FULLW ? MP2 + i * 16384 : MP2;

        if (!FULLW) k_mpad<<<128, 256, 0, stream>>>(w1, w2, (u16*)mp1, (u16*)mp2);

        // ---------- gkpc ----------
        k_xin_lnc<<<GLN, 256, 0, stream>>>(X, alg, alb, XIN, T1, MROWS);
        if (!FULLW) k_f2b<<<CV_QKV, 256, 0, stream>>>((const float4*)q1w, (ushort4*)WSCR, 1536 * 512 / 4);
        if (FAST) {
            k_gemm2<0, 12><<<GQF, 256, 0, stream>>>(T1, wq1p, q1b, YCH, nullptr, nullptr, 1536);
            k_attn<<<GATT, 256, 0, stream>>>(YCH, T2, shift, 0, l2ch, NPID);
        } else {
            for (int hg = 0; hg < NCH; hg++) {
                k_gemm<1, 0><<<GEMM_C, 256, 0, stream>>>(T1, WSCR, q1b, YCH, nullptr, nullptr, hg << shift, shift);
                k_attn<<<GATT, 256, 0, stream>>>(YCH, T2, shift, hg << shift, l2ch, NPID);
            }
        }
        if (!FULLW) k_f2b<<<CV_P, 256, 0, stream>>>((const float4*)pw1, (ushort4*)WSCR, 512 * 512 / 4);
        if (FAST) k_gemm2<1, 4><<<GPF, 256, 0, stream>>>(T2, wp1p, pb1, T1, XIN, nullptr, 512);
        else k_gemm<0, 1><<<GEMM_P, 256, 0, stream>>>(T2, WSCR, pb1, T1, XIN, nullptr, 0, 0);
        k_ln_c<0><<<GLN, 256, 0, stream>>>(T1, alg, alb, T2, MROWS);
        if (!FULLW) k_f2b<<<CV_QKV, 256, 0, stream>>>((const float4*)q2w, (ushort4*)WSCR, 1536 * 512 / 4);
        if (FAST) {
            k_gemm2<0, 12><<<GQF, 256, 0, stream>>>(T2, wq2p, q2b, YCH, nullptr, nullptr, 1536);
            k_attn<<<GATT, 256, 0, stream>>>(YCH, T1, shift, 0, l2ch, NPID);
        } else {
            for (int hg = 0; hg < NCH; hg++) {
                k_gemm<1, 0><<<GEMM_C, 256, 0, stream>>>(T2, WSCR, q2b, YCH, nullptr, nullptr, hg << shift, shift);
                k_attn<<<GATT, 256, 0, stream>>>(YCH, T1, shift, hg << shift, l2ch, NPID);
            }
        }
        if (!FULLW) k_f2b<<<CV_P, 256, 0, stream>>>((const float4*)pw2, (ushort4*)WSCR, 512 * 512 / 4);
        if (FAST) k_gemm2<2, 4><<<GPF, 256, 0, stream>>>(T1, wp2p, pb2, nullptr, nullptr, X, 512);
        else k_gemm<0, 2><<<GEMM_P, 256, 0, stream>>>(T1, WSCR, pb2, nullptr, nullptr, X, 0, 0);

        // ---------- lrsc ----------
        k_ln_j<<<GBC, 256, 0, stream>>>(XIN, l1g, l1b_, T1);
        k_mlp<<<Bn * 2, 512, 0, stream>>>(T1, mp1, b1, mp2, b2, T2);
        if (!FULLW) k_f2b<<<CV_QKV, 256, 0, stream>>>((const float4*)g1w, (ushort4*)WSCR, 1536 * 512 / 4);
        if (FAST) {
            k_gemm2<0, 12><<<GQF, 256, 0, stream>>>(T1, wg1p, g1b, YCH, nullptr, nullptr, 1536);
            k_agg<0><<<GAGG, 256, 0, stream>>>(YCH, adj, XIN, T2, XIN, nullptr, 0, shift);
        } else {
            for (int cc = 0; cc < NCH; cc++) {
                k_gemm<1, 0><<<GEMM_C, 256, 0, stream>>>(T1, WSCR, g1b, YCH, nullptr, nullptr, cc << shift, shift);
                k_agg<0><<<GAGG, 256, 0, stream>>>(YCH, adj, XIN, T2, XIN, nullptr, cc << shift, shift);
            }
        }
        k_ln_c<0><<<GLN, 256, 0, stream>>>(XIN, l2g, l2b_, T1, MROWS);
        k_mlp<<<Bn * 2, 512, 0, stream>>>(T1, mp1, b1, mp2, b2, T2);
        if (!FULLW) k_f2b<<<CV_QKV, 256, 0, stream>>>((const float4*)g2w, (ushort4*)WSCR, 1536 * 512 / 4);
        if (FAST) {
            k_gemm2<0, 12><<<GQF, 256, 0, stream>>>(T1, wg2p, g2b, YCH, nullptr, nullptr, 1536);
            k_agg<1><<<GAGG, 256, 0, stream>>>(YCH, adj, T1, T2, nullptr, X, 0, shift);
        } else {
            for (int cc = 0; cc < NCH; cc++) {
                k_gemm<1, 0><<<GEMM_C, 256, 0, stream>>>(T1, WSCR, g2b, YCH, nullptr, nullptr, cc << shift, shift);
                k_agg<1><<<GAGG, 256, 0, stream>>>(YCH, adj, T1, T2, nullptr, X, cc << shift, shift);
            }
        }
    }

    k_ln_c<1><<<GLN, 256, 0, stream>>>(X, tn_g, tn_b, X, MROWS);
}